// Round 2
// baseline (1385.945 us; speedup 1.0000x reference)
//
#include <hip/hip_runtime.h>
#include <math.h>

// RelationalKENN: two-stage clause enhancer.
// Stage 1 (nodes): u = unary + KE(unary); only cols 0..7 of u are gathered later.
// Stage 2 (edges): clause i softmax(-u1[i], b[i&3], u2[i]); scatter to both nodes + own edge.
// R2: per-XCD privatized accumulators + workgroup-scope (L2-local) atomics to kill
// the 825 MB of memory-side device-atomic traffic seen in R1.

#define NU 16
#define NC 8
#define NXCD 8
// SIMM16 for s_getreg: id=20 (HW_REG_XCC_ID), offset=0, size=4 -> (3<<11)|20
#define XCC_ID_GETREG_IMM 6164

__global__ void zero_acc_kernel(float4* __restrict__ acc, int n4) {
    int i = blockIdx.x * blockDim.x + threadIdx.x;
    int stride = gridDim.x * blockDim.x;
    float4 z; z.x = 0.f; z.y = 0.f; z.z = 0.f; z.w = 0.f;
    for (; i < n4; i += stride) acc[i] = z;
}

__global__ void unary_enhance_kernel(const float* __restrict__ unary,
                                     const float* __restrict__ ucw,
                                     float* __restrict__ out_u,   // [n_nodes*16]
                                     float* __restrict__ u_lo,    // [n_nodes*8]
                                     int n_nodes) {
    int n = blockIdx.x * blockDim.x + threadIdx.x;
    if (n >= n_nodes) return;

    float x[NU];
    const float4* src = (const float4*)(unary + (size_t)n * NU);
#pragma unroll
    for (int j = 0; j < 4; ++j) {
        float4 v = src[j];
        x[4*j+0] = v.x; x[4*j+1] = v.y; x[4*j+2] = v.z; x[4*j+3] = v.w;
    }

    float dlt[NU];
#pragma unroll
    for (int j = 0; j < NU; ++j) dlt[j] = 0.0f;

#pragma unroll
    for (int i = 0; i < NC; ++i) {
        float w = ucw[i];
        float a = -x[i], b = x[i+1], c = x[i+2];
        float m = fmaxf(a, fmaxf(b, c));
        float e0 = __expf(a - m);
        float e1 = __expf(b - m);
        float e2 = __expf(c - m);
        float inv = 1.0f / (e0 + e1 + e2);
        dlt[i]   -= w * e0 * inv;
        dlt[i+1] += w * e1 * inv;
        dlt[i+2] += w * e2 * inv;
    }

    float u[NU];
#pragma unroll
    for (int j = 0; j < NU; ++j) u[j] = x[j] + dlt[j];

    float4* dst = (float4*)(out_u + (size_t)n * NU);
#pragma unroll
    for (int j = 0; j < 4; ++j) {
        float4 v; v.x = u[4*j+0]; v.y = u[4*j+1]; v.z = u[4*j+2]; v.w = u[4*j+3];
        dst[j] = v;
    }
    float4* lo = (float4*)(u_lo + (size_t)n * 8);
    float4 l0; l0.x = u[0]; l0.y = u[1]; l0.z = u[2]; l0.w = u[3];
    float4 l1; l1.x = u[4]; l1.y = u[5]; l1.z = u[6]; l1.w = u[7];
    lo[0] = l0; lo[1] = l1;
}

__device__ __forceinline__ void edge_compute(const float* __restrict__ bcw,
                                             const float* u1, const float* u2,
                                             const float* b,
                                             float* d1, float* d2, float* dbp) {
    dbp[0] = dbp[1] = dbp[2] = dbp[3] = 0.0f;
#pragma unroll
    for (int i = 0; i < NC; ++i) {
        float w = bcw[i];
        float a = -u1[i];
        float bb = b[i & 3];
        float c = u2[i];
        float m = fmaxf(a, fmaxf(bb, c));
        float e0 = __expf(a - m);
        float e1 = __expf(bb - m);
        float e2 = __expf(c - m);
        float inv = 1.0f / (e0 + e1 + e2);
        d1[i] = -w * e0 * inv;
        d2[i] =  w * e2 * inv;
        dbp[i & 3] += w * e1 * inv;
    }
}

// Privatized path: workgroup-scope atomics into this XCD's private accumulator.
__global__ void edge_enhance_priv_kernel(const float* __restrict__ binary,
                                         const float* __restrict__ bcw,
                                         const int* __restrict__ index1,
                                         const int* __restrict__ index2,
                                         const float* __restrict__ u_lo,
                                         float* __restrict__ acc,    // [NXCD][n_nodes*8]
                                         float* __restrict__ out_b,  // [n_edges*4]
                                         int n_nodes, int n_edges) {
    int e = blockIdx.x * blockDim.x + threadIdx.x;
    if (e >= n_edges) return;

    unsigned xcd = __builtin_amdgcn_s_getreg(XCC_ID_GETREG_IMM) & (NXCD - 1);
    float* my_acc = acc + (size_t)xcd * (size_t)n_nodes * 8;

    int i1 = index1[e];
    int i2 = index2[e];

    float4 bv = ((const float4*)binary)[e];
    float b[4] = {bv.x, bv.y, bv.z, bv.w};

    float u1[8], u2[8];
    {
        const float4* p1 = (const float4*)(u_lo + (size_t)i1 * 8);
        float4 a0 = p1[0], a1 = p1[1];
        u1[0]=a0.x; u1[1]=a0.y; u1[2]=a0.z; u1[3]=a0.w;
        u1[4]=a1.x; u1[5]=a1.y; u1[6]=a1.z; u1[7]=a1.w;
        const float4* p2 = (const float4*)(u_lo + (size_t)i2 * 8);
        float4 c0 = p2[0], c1 = p2[1];
        u2[0]=c0.x; u2[1]=c0.y; u2[2]=c0.z; u2[3]=c0.w;
        u2[4]=c1.x; u2[5]=c1.y; u2[6]=c1.z; u2[7]=c1.w;
    }

    float d1[8], d2[8], dbp[4];
    edge_compute(bcw, u1, u2, b, d1, d2, dbp);

    float* r1 = my_acc + (size_t)i1 * 8;
#pragma unroll
    for (int i = 0; i < NC; ++i)
        __hip_atomic_fetch_add(r1 + i, d1[i], __ATOMIC_RELAXED, __HIP_MEMORY_SCOPE_WORKGROUP);
    float* r2 = my_acc + (size_t)i2 * 8;
#pragma unroll
    for (int i = 0; i < NC; ++i)
        __hip_atomic_fetch_add(r2 + i, d2[i], __ATOMIC_RELAXED, __HIP_MEMORY_SCOPE_WORKGROUP);

    float4 ob;
    ob.x = b[0] + dbp[0];
    ob.y = b[1] + dbp[1];
    ob.z = b[2] + dbp[2];
    ob.w = b[3] + dbp[3];
    ((float4*)out_b)[e] = ob;
}

// Fold the 8 per-XCD copies into out_u (cols 0..7 of each row).
__global__ void reduce_acc_kernel(const float* __restrict__ acc,
                                  float* __restrict__ out_u,
                                  int n_nodes) {
    int n = blockIdx.x * blockDim.x + threadIdx.x;
    if (n >= n_nodes) return;

    float s[8];
#pragma unroll
    for (int j = 0; j < 8; ++j) s[j] = 0.0f;

#pragma unroll
    for (int x = 0; x < NXCD; ++x) {
        const float4* p = (const float4*)(acc + ((size_t)x * n_nodes + n) * 8);
        float4 a0 = p[0], a1 = p[1];
        s[0] += a0.x; s[1] += a0.y; s[2] += a0.z; s[3] += a0.w;
        s[4] += a1.x; s[5] += a1.y; s[6] += a1.z; s[7] += a1.w;
    }

    float4* row = (float4*)(out_u + (size_t)n * NU);
    float4 r0 = row[0], r1 = row[1];
    r0.x += s[0]; r0.y += s[1]; r0.z += s[2]; r0.w += s[3];
    r1.x += s[4]; r1.y += s[5]; r1.z += s[6]; r1.w += s[7];
    row[0] = r0; row[1] = r1;
}

// Fallback (R1 behavior): direct device-scope atomics into out_u.
__global__ void edge_enhance_kernel(const float* __restrict__ binary,
                                    const float* __restrict__ bcw,
                                    const int* __restrict__ index1,
                                    const int* __restrict__ index2,
                                    const float* __restrict__ u_lo,
                                    float* __restrict__ out_u,
                                    float* __restrict__ out_b,
                                    int n_edges) {
    int e = blockIdx.x * blockDim.x + threadIdx.x;
    if (e >= n_edges) return;

    int i1 = index1[e];
    int i2 = index2[e];

    float4 bv = ((const float4*)binary)[e];
    float b[4] = {bv.x, bv.y, bv.z, bv.w};

    float u1[8], u2[8];
    {
        const float4* p1 = (const float4*)(u_lo + (size_t)i1 * 8);
        float4 a0 = p1[0], a1 = p1[1];
        u1[0]=a0.x; u1[1]=a0.y; u1[2]=a0.z; u1[3]=a0.w;
        u1[4]=a1.x; u1[5]=a1.y; u1[6]=a1.z; u1[7]=a1.w;
        const float4* p2 = (const float4*)(u_lo + (size_t)i2 * 8);
        float4 c0 = p2[0], c1 = p2[1];
        u2[0]=c0.x; u2[1]=c0.y; u2[2]=c0.z; u2[3]=c0.w;
        u2[4]=c1.x; u2[5]=c1.y; u2[6]=c1.z; u2[7]=c1.w;
    }

    float d1[8], d2[8], dbp[4];
    edge_compute(bcw, u1, u2, b, d1, d2, dbp);

    float* r1 = out_u + (size_t)i1 * NU;
#pragma unroll
    for (int i = 0; i < NC; ++i) atomicAdd(r1 + i, d1[i]);
    float* r2 = out_u + (size_t)i2 * NU;
#pragma unroll
    for (int i = 0; i < NC; ++i) atomicAdd(r2 + i, d2[i]);

    float4 ob;
    ob.x = b[0] + dbp[0];
    ob.y = b[1] + dbp[1];
    ob.z = b[2] + dbp[2];
    ob.w = b[3] + dbp[3];
    ((float4*)out_b)[e] = ob;
}

extern "C" void kernel_launch(void* const* d_in, const int* in_sizes, int n_in,
                              void* d_out, int out_size, void* d_ws, size_t ws_size,
                              hipStream_t stream) {
    const float* unary  = (const float*)d_in[0];
    const float* binary = (const float*)d_in[1];
    const float* ucw    = (const float*)d_in[2];
    const float* bcw    = (const float*)d_in[3];
    const int*   index1 = (const int*)d_in[4];
    const int*   index2 = (const int*)d_in[5];

    int n_nodes = in_sizes[0] / NU;
    int n_edges = in_sizes[4];

    float* out_u = (float*)d_out;                   // n_nodes*16
    float* out_b = out_u + (size_t)n_nodes * NU;    // n_edges*4

    // ws layout: u_lo [n_nodes*8] | acc [NXCD][n_nodes*8]
    float* u_lo = (float*)d_ws;
    float* acc  = u_lo + (size_t)n_nodes * 8;
    size_t acc_floats = (size_t)NXCD * n_nodes * 8;
    size_t need_bytes = ((size_t)n_nodes * 8 + acc_floats) * sizeof(float);

    int tb = 256;
    unary_enhance_kernel<<<(n_nodes + tb - 1) / tb, tb, 0, stream>>>(
        unary, ucw, out_u, u_lo, n_nodes);

    if (ws_size >= need_bytes) {
        int n4 = (int)(acc_floats / 4);
        zero_acc_kernel<<<1024, 256, 0, stream>>>((float4*)acc, n4);
        edge_enhance_priv_kernel<<<(n_edges + tb - 1) / tb, tb, 0, stream>>>(
            binary, bcw, index1, index2, u_lo, acc, out_b, n_nodes, n_edges);
        reduce_acc_kernel<<<(n_nodes + tb - 1) / tb, tb, 0, stream>>>(
            acc, out_u, n_nodes);
    } else {
        edge_enhance_kernel<<<(n_edges + tb - 1) / tb, tb, 0, stream>>>(
            binary, bcw, index1, index2, u_lo, out_u, out_b, n_edges);
    }
}

// Round 3
// 1260.038 us; speedup vs baseline: 1.0999x; 1.0999x over previous
//
#include <hip/hip_runtime.h>
#include <math.h>

// RelationalKENN R3: node-tiled LDS scatter — zero global atomics.
// R1/R2 showed 25.6M memory-side atomic messages (825MB WRITE_SIZE) bound the
// kernel at ~20G msg/s. Here: 49 tiles x 2048 nodes, accumulate in 64KB LDS
// with LDS atomics, scan a 2B/edge tile-tag array (L2-resident) to find hits,
// dump per-(tile,replica) partials, merge. out_b via separate coalesced pass.

#define NU 16
#define NC 8
#define TILE_SHIFT 11
#define TILE_NODES 2048          // 2048*8*4B = 64KB LDS
#define RREP 6                   // edge-slice replicas per tile
#define SCAN_BT 512

__global__ void tt_pack_kernel(const int* __restrict__ i1,
                               const int* __restrict__ i2,
                               unsigned short* __restrict__ tt, int n_edges) {
    int e = blockIdx.x * blockDim.x + threadIdx.x;
    if (e >= n_edges) return;
    unsigned t1 = ((unsigned)i1[e]) >> TILE_SHIFT;
    unsigned t2 = ((unsigned)i2[e]) >> TILE_SHIFT;
    tt[e] = (unsigned short)(t1 | (t2 << 8));
}

__global__ void unary_enhance_kernel(const float* __restrict__ unary,
                                     const float* __restrict__ ucw,
                                     float* __restrict__ out_u,   // [n_nodes*16]
                                     float* __restrict__ u_lo,    // [n_nodes*8]
                                     int n_nodes) {
    int n = blockIdx.x * blockDim.x + threadIdx.x;
    if (n >= n_nodes) return;

    float x[NU];
    const float4* src = (const float4*)(unary + (size_t)n * NU);
#pragma unroll
    for (int j = 0; j < 4; ++j) {
        float4 v = src[j];
        x[4*j+0] = v.x; x[4*j+1] = v.y; x[4*j+2] = v.z; x[4*j+3] = v.w;
    }
    float dlt[NU];
#pragma unroll
    for (int j = 0; j < NU; ++j) dlt[j] = 0.0f;
#pragma unroll
    for (int i = 0; i < NC; ++i) {
        float w = ucw[i];
        float a = -x[i], b = x[i+1], c = x[i+2];
        float m = fmaxf(a, fmaxf(b, c));
        float e0 = __expf(a - m);
        float e1 = __expf(b - m);
        float e2 = __expf(c - m);
        float inv = 1.0f / (e0 + e1 + e2);
        dlt[i]   -= w * e0 * inv;
        dlt[i+1] += w * e1 * inv;
        dlt[i+2] += w * e2 * inv;
    }
    float u[NU];
#pragma unroll
    for (int j = 0; j < NU; ++j) u[j] = x[j] + dlt[j];

    float4* dst = (float4*)(out_u + (size_t)n * NU);
#pragma unroll
    for (int j = 0; j < 4; ++j) {
        float4 v; v.x = u[4*j+0]; v.y = u[4*j+1]; v.z = u[4*j+2]; v.w = u[4*j+3];
        dst[j] = v;
    }
    float4* lo = (float4*)(u_lo + (size_t)n * 8);
    float4 l0; l0.x = u[0]; l0.y = u[1]; l0.z = u[2]; l0.w = u[3];
    float4 l1; l1.x = u[4]; l1.y = u[5]; l1.z = u[6]; l1.w = u[7];
    lo[0] = l0; lo[1] = l1;
}

// out_b pass: coalesced, no scatter.
__global__ void edge_b_kernel(const float* __restrict__ binary,
                              const float* __restrict__ bcw,
                              const int* __restrict__ index1,
                              const int* __restrict__ index2,
                              const float* __restrict__ u_lo,
                              float* __restrict__ out_b,
                              int n_edges) {
    int e = blockIdx.x * blockDim.x + threadIdx.x;
    if (e >= n_edges) return;

    int i1 = index1[e];
    int i2 = index2[e];
    float4 bv = ((const float4*)binary)[e];
    float b[4] = {bv.x, bv.y, bv.z, bv.w};

    const float4* p1 = (const float4*)(u_lo + (size_t)i1 * 8);
    float4 a0 = p1[0], a1 = p1[1];
    const float4* p2 = (const float4*)(u_lo + (size_t)i2 * 8);
    float4 c0 = p2[0], c1 = p2[1];
    float u1[8] = {a0.x,a0.y,a0.z,a0.w,a1.x,a1.y,a1.z,a1.w};
    float u2[8] = {c0.x,c0.y,c0.z,c0.w,c1.x,c1.y,c1.z,c1.w};

    float dbp[4] = {0.f, 0.f, 0.f, 0.f};
#pragma unroll
    for (int i = 0; i < NC; ++i) {
        float w = bcw[i];
        float a = -u1[i], bb = b[i & 3], c = u2[i];
        float m = fmaxf(a, fmaxf(bb, c));
        float e0 = __expf(a - m);
        float e1 = __expf(bb - m);
        float e2 = __expf(c - m);
        dbp[i & 3] += w * e1 / (e0 + e1 + e2);
    }
    float4 ob;
    ob.x = b[0] + dbp[0];
    ob.y = b[1] + dbp[1];
    ob.z = b[2] + dbp[2];
    ob.w = b[3] + dbp[3];
    ((float4*)out_b)[e] = ob;
}

// Tile-scan scatter: block (tile t, replica r) scans edge slice, accumulates
// hits into LDS via LDS atomics, dumps partial to workspace.
__global__ __launch_bounds__(SCAN_BT)
void tile_scatter_kernel(const float* __restrict__ binary,
                         const float* __restrict__ bcw,
                         const int* __restrict__ index1,
                         const int* __restrict__ index2,
                         const float* __restrict__ u_lo,
                         const unsigned short* __restrict__ tt,
                         float* __restrict__ partials,  // [T*RREP][TILE_NODES*8]
                         int n_edges, int chunk) {
    __shared__ float acc[TILE_NODES * 8];
    int tid = threadIdx.x;
    for (int i = tid; i < TILE_NODES * 8; i += SCAN_BT) acc[i] = 0.0f;
    __syncthreads();

    int my_tile = blockIdx.x;
    int tbase = my_tile << TILE_SHIFT;
    int e_begin = blockIdx.y * chunk;
    int e_end = e_begin + chunk;
    if (e_end > n_edges) e_end = n_edges;

    float w[NC];
#pragma unroll
    for (int i = 0; i < NC; ++i) w[i] = bcw[i];

    for (int base = e_begin + tid * 4; base < e_end; base += SCAN_BT * 4) {
        ushort4 tv = *(const ushort4*)(tt + base);  // chunk%4==0 -> aligned
        unsigned short ts[4] = {tv.x, tv.y, tv.z, tv.w};
#pragma unroll
        for (int k = 0; k < 4; ++k) {
            int e = base + k;
            if (e >= e_end) continue;
            int t1 = ts[k] & 0xFF;
            int t2 = ts[k] >> 8;
            bool h1 = (t1 == my_tile);
            bool h2 = (t2 == my_tile);
            if (!(h1 || h2)) continue;

            int i1 = index1[e];
            int i2 = index2[e];
            const float4* p1 = (const float4*)(u_lo + (size_t)i1 * 8);
            float4 a0 = p1[0], a1 = p1[1];
            const float4* p2 = (const float4*)(u_lo + (size_t)i2 * 8);
            float4 c0 = p2[0], c1 = p2[1];
            float u1[8] = {a0.x,a0.y,a0.z,a0.w,a1.x,a1.y,a1.z,a1.w};
            float u2[8] = {c0.x,c0.y,c0.z,c0.w,c1.x,c1.y,c1.z,c1.w};
            float4 bv = ((const float4*)binary)[e];
            float b[4] = {bv.x, bv.y, bv.z, bv.w};

            float d1[8], d2[8];
#pragma unroll
            for (int i = 0; i < NC; ++i) {
                float a = -u1[i], bb = b[i & 3], c = u2[i];
                float m = fmaxf(a, fmaxf(bb, c));
                float e0 = __expf(a - m);
                float e1 = __expf(bb - m);
                float e2 = __expf(c - m);
                float inv = 1.0f / (e0 + e1 + e2);
                d1[i] = -w[i] * e0 * inv;
                d2[i] =  w[i] * e2 * inv;
            }
            if (h1) {
                float* r = acc + (size_t)(i1 - tbase) * 8;
#pragma unroll
                for (int i = 0; i < NC; ++i) atomicAdd(r + i, d1[i]);
            }
            if (h2) {
                float* r = acc + (size_t)(i2 - tbase) * 8;
#pragma unroll
                for (int i = 0; i < NC; ++i) atomicAdd(r + i, d2[i]);
            }
        }
    }
    __syncthreads();

    float* dst = partials + ((size_t)my_tile * RREP + blockIdx.y) * (TILE_NODES * 8);
    for (int i = tid; i < TILE_NODES * 2; i += SCAN_BT)
        ((float4*)dst)[i] = ((const float4*)acc)[i];
}

__global__ void merge_kernel(const float* __restrict__ partials,
                             float* __restrict__ out_u, int n_nodes) {
    int n = blockIdx.x * blockDim.x + threadIdx.x;
    if (n >= n_nodes) return;
    int t = n >> TILE_SHIFT;
    int local = n & (TILE_NODES - 1);

    float s[8];
#pragma unroll
    for (int j = 0; j < 8; ++j) s[j] = 0.0f;
    for (int r = 0; r < RREP; ++r) {
        const float4* p = (const float4*)(partials +
            ((size_t)t * RREP + r) * (TILE_NODES * 8) + (size_t)local * 8);
        float4 a = p[0], b = p[1];
        s[0] += a.x; s[1] += a.y; s[2] += a.z; s[3] += a.w;
        s[4] += b.x; s[5] += b.y; s[6] += b.z; s[7] += b.w;
    }
    float4* row = (float4*)(out_u + (size_t)n * NU);
    float4 r0 = row[0], r1 = row[1];
    r0.x += s[0]; r0.y += s[1]; r0.z += s[2]; r0.w += s[3];
    r1.x += s[4]; r1.y += s[5]; r1.z += s[6]; r1.w += s[7];
    row[0] = r0; row[1] = r1;
}

// Fallback (R1): device-scope atomics, needs only u_lo in ws.
__global__ void edge_enhance_kernel(const float* __restrict__ binary,
                                    const float* __restrict__ bcw,
                                    const int* __restrict__ index1,
                                    const int* __restrict__ index2,
                                    const float* __restrict__ u_lo,
                                    float* __restrict__ out_u,
                                    float* __restrict__ out_b,
                                    int n_edges) {
    int e = blockIdx.x * blockDim.x + threadIdx.x;
    if (e >= n_edges) return;

    int i1 = index1[e];
    int i2 = index2[e];
    float4 bv = ((const float4*)binary)[e];
    float b[4] = {bv.x, bv.y, bv.z, bv.w};

    const float4* p1 = (const float4*)(u_lo + (size_t)i1 * 8);
    float4 a0 = p1[0], a1 = p1[1];
    const float4* p2 = (const float4*)(u_lo + (size_t)i2 * 8);
    float4 c0 = p2[0], c1 = p2[1];
    float u1[8] = {a0.x,a0.y,a0.z,a0.w,a1.x,a1.y,a1.z,a1.w};
    float u2[8] = {c0.x,c0.y,c0.z,c0.w,c1.x,c1.y,c1.z,c1.w};

    float d1[8], d2[8], dbp[4] = {0.f,0.f,0.f,0.f};
#pragma unroll
    for (int i = 0; i < NC; ++i) {
        float w = bcw[i];
        float a = -u1[i], bb = b[i & 3], c = u2[i];
        float m = fmaxf(a, fmaxf(bb, c));
        float e0 = __expf(a - m);
        float e1 = __expf(bb - m);
        float e2 = __expf(c - m);
        float inv = 1.0f / (e0 + e1 + e2);
        d1[i] = -w * e0 * inv;
        d2[i] =  w * e2 * inv;
        dbp[i & 3] += w * e1 * inv;
    }
    float* r1 = out_u + (size_t)i1 * NU;
#pragma unroll
    for (int i = 0; i < NC; ++i) atomicAdd(r1 + i, d1[i]);
    float* r2 = out_u + (size_t)i2 * NU;
#pragma unroll
    for (int i = 0; i < NC; ++i) atomicAdd(r2 + i, d2[i]);

    float4 ob;
    ob.x = b[0] + dbp[0];
    ob.y = b[1] + dbp[1];
    ob.z = b[2] + dbp[2];
    ob.w = b[3] + dbp[3];
    ((float4*)out_b)[e] = ob;
}

extern "C" void kernel_launch(void* const* d_in, const int* in_sizes, int n_in,
                              void* d_out, int out_size, void* d_ws, size_t ws_size,
                              hipStream_t stream) {
    const float* unary  = (const float*)d_in[0];
    const float* binary = (const float*)d_in[1];
    const float* ucw    = (const float*)d_in[2];
    const float* bcw    = (const float*)d_in[3];
    const int*   index1 = (const int*)d_in[4];
    const int*   index2 = (const int*)d_in[5];

    int n_nodes = in_sizes[0] / NU;
    int n_edges = in_sizes[4];

    float* out_u = (float*)d_out;
    float* out_b = out_u + (size_t)n_nodes * NU;

    int T = (n_nodes + TILE_NODES - 1) >> TILE_SHIFT;

    // ws layout (bytes): u_lo | tt (16B-aligned) | partials
    size_t u_lo_bytes = (size_t)n_nodes * 8 * sizeof(float);
    size_t tt_off = (u_lo_bytes + 15) & ~(size_t)15;
    size_t tt_bytes = ((size_t)n_edges * 2 + 15) & ~(size_t)15;
    size_t part_off = tt_off + tt_bytes;
    size_t part_bytes = (size_t)T * RREP * TILE_NODES * 8 * sizeof(float);
    size_t need = part_off + part_bytes;

    float* u_lo = (float*)d_ws;
    unsigned short* tt = (unsigned short*)((char*)d_ws + tt_off);
    float* partials = (float*)((char*)d_ws + part_off);

    int tb = 256;
    unary_enhance_kernel<<<(n_nodes + tb - 1) / tb, tb, 0, stream>>>(
        unary, ucw, out_u, u_lo, n_nodes);

    if (ws_size >= need && T <= 256) {
        tt_pack_kernel<<<(n_edges + tb - 1) / tb, tb, 0, stream>>>(
            index1, index2, tt, n_edges);
        edge_b_kernel<<<(n_edges + tb - 1) / tb, tb, 0, stream>>>(
            binary, bcw, index1, index2, u_lo, out_b, n_edges);
        int chunk = (n_edges + RREP - 1) / RREP;
        chunk = (chunk + 3) & ~3;
        dim3 grid(T, RREP);
        tile_scatter_kernel<<<grid, SCAN_BT, 0, stream>>>(
            binary, bcw, index1, index2, u_lo, tt, partials, n_edges, chunk);
        merge_kernel<<<(n_nodes + tb - 1) / tb, tb, 0, stream>>>(
            partials, out_u, n_nodes);
    } else {
        edge_enhance_kernel<<<(n_edges + tb - 1) / tb, tb, 0, stream>>>(
            binary, bcw, index1, index2, u_lo, out_u, out_b, n_edges);
    }
}

// Round 4
// 440.633 us; speedup vs baseline: 3.1454x; 2.8596x over previous
//
#include <hip/hip_runtime.h>
#include <math.h>

// RelationalKENN R4: counting-sort binning + dense tile accumulation.
// R1/R2: 25.6M memory-side atomics (825MB) -> ~20G msg/s wall.
// R3: LDS tiles killed atomics but O(T*E) divergent scan (4% hit rate) kept it at 1.15ms.
// R4: O(E) bin pass reserves per-(block,bin) ranges with ONE global atomic each
// (~200k total), scatters (u16 local id, 8x bf16 d) payloads; then per-tile dense
// LDS accumulation with all lanes active. out_b fused into the bin pass.

#define NU 16
#define NC 8
#define TILE_N 128
#define TILE_SHIFT 7
#define NB 256        // bin-pass blocks
#define BT 256        // bin-pass block size
#define MAXB 1024     // max tiles supported by LDS histogram

__device__ __forceinline__ unsigned short f2bf(float x) {
    unsigned b = __float_as_uint(x);
    unsigned r = (b + 0x7fffu + ((b >> 16) & 1u)) >> 16;
    return (unsigned short)r;
}
__device__ __forceinline__ float bf2f(unsigned h) {
    return __uint_as_float(h << 16);
}

__global__ void unary_enhance_kernel(const float* __restrict__ unary,
                                     const float* __restrict__ ucw,
                                     float* __restrict__ out_u,   // [n_nodes*16]
                                     float* __restrict__ u_lo,    // [n_nodes*8]
                                     int n_nodes) {
    int n = blockIdx.x * blockDim.x + threadIdx.x;
    if (n >= n_nodes) return;

    float x[NU];
    const float4* src = (const float4*)(unary + (size_t)n * NU);
#pragma unroll
    for (int j = 0; j < 4; ++j) {
        float4 v = src[j];
        x[4*j+0] = v.x; x[4*j+1] = v.y; x[4*j+2] = v.z; x[4*j+3] = v.w;
    }
    float dlt[NU];
#pragma unroll
    for (int j = 0; j < NU; ++j) dlt[j] = 0.0f;
#pragma unroll
    for (int i = 0; i < NC; ++i) {
        float w = ucw[i];
        float a = -x[i], b = x[i+1], c = x[i+2];
        float m = fmaxf(a, fmaxf(b, c));
        float e0 = __expf(a - m);
        float e1 = __expf(b - m);
        float e2 = __expf(c - m);
        float inv = 1.0f / (e0 + e1 + e2);
        dlt[i]   -= w * e0 * inv;
        dlt[i+1] += w * e1 * inv;
        dlt[i+2] += w * e2 * inv;
    }
    float u[NU];
#pragma unroll
    for (int j = 0; j < NU; ++j) u[j] = x[j] + dlt[j];

    float4* dst = (float4*)(out_u + (size_t)n * NU);
#pragma unroll
    for (int j = 0; j < 4; ++j) {
        float4 v; v.x = u[4*j+0]; v.y = u[4*j+1]; v.z = u[4*j+2]; v.w = u[4*j+3];
        dst[j] = v;
    }
    float4* lo = (float4*)(u_lo + (size_t)n * 8);
    float4 l0; l0.x = u[0]; l0.y = u[1]; l0.z = u[2]; l0.w = u[3];
    float4 l1; l1.x = u[4]; l1.y = u[5]; l1.z = u[6]; l1.w = u[7];
    lo[0] = l0; lo[1] = l1;
}

__global__ __launch_bounds__(BT)
void bin_edges_kernel(const float* __restrict__ binary,
                      const float* __restrict__ bcw,
                      const int* __restrict__ index1,
                      const int* __restrict__ index2,
                      const float* __restrict__ u_lo,
                      float* __restrict__ out_b,       // [n_edges*4]
                      unsigned* __restrict__ cursor,   // [T], zeroed
                      unsigned short* __restrict__ ids,// [T*cap]
                      uint4* __restrict__ dvals,       // [T*cap]
                      float* __restrict__ out_u,       // overflow path only
                      int n_edges, int T, int cap, int chunk) {
    __shared__ unsigned hist[MAXB];
    int tid = threadIdx.x;
    for (int t = tid; t < T; t += BT) hist[t] = 0u;
    __syncthreads();

    int e0 = blockIdx.x * chunk;
    int e1 = e0 + chunk; if (e1 > n_edges) e1 = n_edges;

    // pass 1: local histogram
    for (int e = e0 + tid; e < e1; e += BT) {
        unsigned t1 = ((unsigned)index1[e]) >> TILE_SHIFT;
        unsigned t2 = ((unsigned)index2[e]) >> TILE_SHIFT;
        atomicAdd(&hist[t1], 1u);
        atomicAdd(&hist[t2], 1u);
    }
    __syncthreads();

    // reserve ranges: one global atomic per (block, nonzero bin)
    for (int t = tid; t < T; t += BT) {
        unsigned c = hist[t];
        unsigned base = 0u;
        if (c) base = atomicAdd(&cursor[t], c);
        hist[t] = base;   // becomes the LDS slot cursor
    }
    __syncthreads();

    float w[NC];
#pragma unroll
    for (int i = 0; i < NC; ++i) w[i] = bcw[i];

    // pass 2: compute clause deltas, write out_b, scatter payloads
    for (int e = e0 + tid; e < e1; e += BT) {
        int i1 = index1[e];
        int i2 = index2[e];
        float4 bv = ((const float4*)binary)[e];
        float b[4] = {bv.x, bv.y, bv.z, bv.w};

        const float4* p1 = (const float4*)(u_lo + (size_t)i1 * 8);
        float4 a0 = p1[0], a1 = p1[1];
        const float4* p2 = (const float4*)(u_lo + (size_t)i2 * 8);
        float4 c0 = p2[0], c1 = p2[1];
        float u1[8] = {a0.x,a0.y,a0.z,a0.w,a1.x,a1.y,a1.z,a1.w};
        float u2[8] = {c0.x,c0.y,c0.z,c0.w,c1.x,c1.y,c1.z,c1.w};

        float d1[8], d2[8], dbp[4] = {0.f,0.f,0.f,0.f};
#pragma unroll
        for (int i = 0; i < NC; ++i) {
            float a = -u1[i], bb = b[i & 3], c = u2[i];
            float m = fmaxf(a, fmaxf(bb, c));
            float e0x = __expf(a - m);
            float e1x = __expf(bb - m);
            float e2x = __expf(c - m);
            float inv = 1.0f / (e0x + e1x + e2x);
            d1[i] = -w[i] * e0x * inv;
            d2[i] =  w[i] * e2x * inv;
            dbp[i & 3] += w[i] * e1x * inv;
        }
        float4 ob;
        ob.x = b[0] + dbp[0];
        ob.y = b[1] + dbp[1];
        ob.z = b[2] + dbp[2];
        ob.w = b[3] + dbp[3];
        ((float4*)out_b)[e] = ob;

        unsigned t1 = ((unsigned)i1) >> TILE_SHIFT;
        unsigned slot1 = atomicAdd(&hist[t1], 1u);
        if (slot1 < (unsigned)cap) {
            size_t p = (size_t)t1 * cap + slot1;
            ids[p] = (unsigned short)(i1 & (TILE_N - 1));
            uint4 v;
            v.x = (unsigned)f2bf(d1[0]) | ((unsigned)f2bf(d1[1]) << 16);
            v.y = (unsigned)f2bf(d1[2]) | ((unsigned)f2bf(d1[3]) << 16);
            v.z = (unsigned)f2bf(d1[4]) | ((unsigned)f2bf(d1[5]) << 16);
            v.w = (unsigned)f2bf(d1[6]) | ((unsigned)f2bf(d1[7]) << 16);
            dvals[p] = v;
        } else {
            float* r = out_u + (size_t)i1 * NU;
#pragma unroll
            for (int i = 0; i < NC; ++i) atomicAdd(r + i, d1[i]);
        }

        unsigned t2 = ((unsigned)i2) >> TILE_SHIFT;
        unsigned slot2 = atomicAdd(&hist[t2], 1u);
        if (slot2 < (unsigned)cap) {
            size_t p = (size_t)t2 * cap + slot2;
            ids[p] = (unsigned short)(i2 & (TILE_N - 1));
            uint4 v;
            v.x = (unsigned)f2bf(d2[0]) | ((unsigned)f2bf(d2[1]) << 16);
            v.y = (unsigned)f2bf(d2[2]) | ((unsigned)f2bf(d2[3]) << 16);
            v.z = (unsigned)f2bf(d2[4]) | ((unsigned)f2bf(d2[5]) << 16);
            v.w = (unsigned)f2bf(d2[6]) | ((unsigned)f2bf(d2[7]) << 16);
            dvals[p] = v;
        } else {
            float* r = out_u + (size_t)i2 * NU;
#pragma unroll
            for (int i = 0; i < NC; ++i) atomicAdd(r + i, d2[i]);
        }
    }
}

__global__ __launch_bounds__(256)
void tile_acc_kernel(const unsigned* __restrict__ cursor,
                     const unsigned short* __restrict__ ids,
                     const uint4* __restrict__ dvals,
                     float* __restrict__ out_u,
                     int n_nodes, int cap) {
    __shared__ float acc[TILE_N * 8];
    int t = blockIdx.x;
    int tid = threadIdx.x;
    for (int i = tid; i < TILE_N * 8; i += 256) acc[i] = 0.0f;
    __syncthreads();

    unsigned cnt = cursor[t];
    if (cnt > (unsigned)cap) cnt = (unsigned)cap;
    size_t base = (size_t)t * cap;

    for (unsigned i = tid; i < cnt; i += 256) {
        int id = ids[base + i];
        uint4 v = dvals[base + i];
        float* r = acc + id * 8;
        atomicAdd(r + 0, bf2f(v.x & 0xffffu));
        atomicAdd(r + 1, bf2f(v.x >> 16));
        atomicAdd(r + 2, bf2f(v.y & 0xffffu));
        atomicAdd(r + 3, bf2f(v.y >> 16));
        atomicAdd(r + 4, bf2f(v.z & 0xffffu));
        atomicAdd(r + 5, bf2f(v.z >> 16));
        atomicAdd(r + 6, bf2f(v.w & 0xffffu));
        atomicAdd(r + 7, bf2f(v.w >> 16));
    }
    __syncthreads();

    int nbase = t << TILE_SHIFT;
    for (int l = tid; l < TILE_N; l += 256) {
        int n = nbase + l;
        if (n >= n_nodes) continue;
        float4* row = (float4*)(out_u + (size_t)n * NU);
        float4 r0 = row[0], r1 = row[1];
        const float* a = acc + l * 8;
        r0.x += a[0]; r0.y += a[1]; r0.z += a[2]; r0.w += a[3];
        r1.x += a[4]; r1.y += a[5]; r1.z += a[6]; r1.w += a[7];
        row[0] = r0; row[1] = r1;
    }
}

// Fallback (R1): device-scope atomics, needs only u_lo in ws.
__global__ void edge_enhance_kernel(const float* __restrict__ binary,
                                    const float* __restrict__ bcw,
                                    const int* __restrict__ index1,
                                    const int* __restrict__ index2,
                                    const float* __restrict__ u_lo,
                                    float* __restrict__ out_u,
                                    float* __restrict__ out_b,
                                    int n_edges) {
    int e = blockIdx.x * blockDim.x + threadIdx.x;
    if (e >= n_edges) return;

    int i1 = index1[e];
    int i2 = index2[e];
    float4 bv = ((const float4*)binary)[e];
    float b[4] = {bv.x, bv.y, bv.z, bv.w};

    const float4* p1 = (const float4*)(u_lo + (size_t)i1 * 8);
    float4 a0 = p1[0], a1 = p1[1];
    const float4* p2 = (const float4*)(u_lo + (size_t)i2 * 8);
    float4 c0 = p2[0], c1 = p2[1];
    float u1[8] = {a0.x,a0.y,a0.z,a0.w,a1.x,a1.y,a1.z,a1.w};
    float u2[8] = {c0.x,c0.y,c0.z,c0.w,c1.x,c1.y,c1.z,c1.w};

    float d1[8], d2[8], dbp[4] = {0.f,0.f,0.f,0.f};
#pragma unroll
    for (int i = 0; i < NC; ++i) {
        float w = bcw[i];
        float a = -u1[i], bb = b[i & 3], c = u2[i];
        float m = fmaxf(a, fmaxf(bb, c));
        float e0 = __expf(a - m);
        float e1 = __expf(bb - m);
        float e2 = __expf(c - m);
        float inv = 1.0f / (e0 + e1 + e2);
        d1[i] = -w * e0 * inv;
        d2[i] =  w * e2 * inv;
        dbp[i & 3] += w * e1 * inv;
    }
    float* r1 = out_u + (size_t)i1 * NU;
#pragma unroll
    for (int i = 0; i < NC; ++i) atomicAdd(r1 + i, d1[i]);
    float* r2 = out_u + (size_t)i2 * NU;
#pragma unroll
    for (int i = 0; i < NC; ++i) atomicAdd(r2 + i, d2[i]);

    float4 ob;
    ob.x = b[0] + dbp[0];
    ob.y = b[1] + dbp[1];
    ob.z = b[2] + dbp[2];
    ob.w = b[3] + dbp[3];
    ((float4*)out_b)[e] = ob;
}

extern "C" void kernel_launch(void* const* d_in, const int* in_sizes, int n_in,
                              void* d_out, int out_size, void* d_ws, size_t ws_size,
                              hipStream_t stream) {
    const float* unary  = (const float*)d_in[0];
    const float* binary = (const float*)d_in[1];
    const float* ucw    = (const float*)d_in[2];
    const float* bcw    = (const float*)d_in[3];
    const int*   index1 = (const int*)d_in[4];
    const int*   index2 = (const int*)d_in[5];

    int n_nodes = in_sizes[0] / NU;
    int n_edges = in_sizes[4];

    float* out_u = (float*)d_out;
    float* out_b = out_u + (size_t)n_nodes * NU;

    int T = (n_nodes + TILE_N - 1) >> TILE_SHIFT;
    size_t mean = (2ull * (size_t)n_edges) / (size_t)T;
    int cap = (int)(mean + mean / 8 + 512);   // +8 sigma headroom; overflow path exists

    // ws layout: u_lo [n_nodes*8 f32] | dvals [T*cap uint4] | ids [T*cap u16] | cursor [T u32]
    size_t u_lo_bytes  = (size_t)n_nodes * 8 * sizeof(float);
    size_t dvals_off   = (u_lo_bytes + 15) & ~(size_t)15;
    size_t dvals_bytes = (size_t)T * cap * sizeof(uint4);
    size_t ids_off     = dvals_off + dvals_bytes;
    size_t ids_bytes   = ((size_t)T * cap * 2 + 3) & ~(size_t)3;
    size_t cur_off     = ids_off + ids_bytes;
    size_t cur_bytes   = (size_t)T * 4;
    size_t need        = cur_off + cur_bytes;

    float* u_lo = (float*)d_ws;
    uint4* dvals = (uint4*)((char*)d_ws + dvals_off);
    unsigned short* ids = (unsigned short*)((char*)d_ws + ids_off);
    unsigned* cursor = (unsigned*)((char*)d_ws + cur_off);

    int tb = 256;
    unary_enhance_kernel<<<(n_nodes + tb - 1) / tb, tb, 0, stream>>>(
        unary, ucw, out_u, u_lo, n_nodes);

    if (ws_size >= need && T <= MAXB) {
        hipMemsetAsync(cursor, 0, cur_bytes, stream);
        int chunk = (n_edges + NB - 1) / NB;
        bin_edges_kernel<<<NB, BT, 0, stream>>>(
            binary, bcw, index1, index2, u_lo, out_b,
            cursor, ids, dvals, out_u, n_edges, T, cap, chunk);
        tile_acc_kernel<<<T, 256, 0, stream>>>(
            cursor, ids, dvals, out_u, n_nodes, cap);
    } else {
        edge_enhance_kernel<<<(n_edges + tb - 1) / tb, tb, 0, stream>>>(
            binary, bcw, index1, index2, u_lo, out_u, out_b, n_edges);
    }
}

// Round 5
// 427.278 us; speedup vs baseline: 3.2437x; 1.0313x over previous
//
#include <hip/hip_runtime.h>
#include <math.h>

// RelationalKENN R5: same counting-sort structure as R4, tuned for latency.
// R4 post-mortem: bin_edges at 9.8% occupancy (1 blk/CU), tile_acc serialized
// (12 VGPRs, 1 outstanding load) + 16-way LDS bank aliasing (acc[id*8+j] maps
// 64 lanes to 4 banks). R5: bigger blocks + launch_bounds VGPR headroom for
// bin pass; column-major acc + 4-entry unrolled loads for the acc pass.

#define NU 16
#define NC 8
#define TILE_N 128
#define TILE_SHIFT 7
#define NB 512        // bin-pass blocks
#define BT 512        // bin-pass block size
#define MAXB 1024     // max tiles supported by LDS histogram

__device__ __forceinline__ unsigned short f2bf(float x) {
    unsigned b = __float_as_uint(x);
    unsigned r = (b + 0x7fffu + ((b >> 16) & 1u)) >> 16;
    return (unsigned short)r;
}
__device__ __forceinline__ float bf2f(unsigned h) {
    return __uint_as_float(h << 16);
}

__global__ void unary_enhance_kernel(const float* __restrict__ unary,
                                     const float* __restrict__ ucw,
                                     float* __restrict__ out_u,   // [n_nodes*16]
                                     float* __restrict__ u_lo,    // [n_nodes*8]
                                     int n_nodes) {
    int n = blockIdx.x * blockDim.x + threadIdx.x;
    if (n >= n_nodes) return;

    float x[NU];
    const float4* src = (const float4*)(unary + (size_t)n * NU);
#pragma unroll
    for (int j = 0; j < 4; ++j) {
        float4 v = src[j];
        x[4*j+0] = v.x; x[4*j+1] = v.y; x[4*j+2] = v.z; x[4*j+3] = v.w;
    }
    float dlt[NU];
#pragma unroll
    for (int j = 0; j < NU; ++j) dlt[j] = 0.0f;
#pragma unroll
    for (int i = 0; i < NC; ++i) {
        float w = ucw[i];
        float a = -x[i], b = x[i+1], c = x[i+2];
        float m = fmaxf(a, fmaxf(b, c));
        float e0 = __expf(a - m);
        float e1 = __expf(b - m);
        float e2 = __expf(c - m);
        float inv = 1.0f / (e0 + e1 + e2);
        dlt[i]   -= w * e0 * inv;
        dlt[i+1] += w * e1 * inv;
        dlt[i+2] += w * e2 * inv;
    }
    float u[NU];
#pragma unroll
    for (int j = 0; j < NU; ++j) u[j] = x[j] + dlt[j];

    float4* dst = (float4*)(out_u + (size_t)n * NU);
#pragma unroll
    for (int j = 0; j < 4; ++j) {
        float4 v; v.x = u[4*j+0]; v.y = u[4*j+1]; v.z = u[4*j+2]; v.w = u[4*j+3];
        dst[j] = v;
    }
    float4* lo = (float4*)(u_lo + (size_t)n * 8);
    float4 l0; l0.x = u[0]; l0.y = u[1]; l0.z = u[2]; l0.w = u[3];
    float4 l1; l1.x = u[4]; l1.y = u[5]; l1.z = u[6]; l1.w = u[7];
    lo[0] = l0; lo[1] = l1;
}

__global__ __launch_bounds__(BT, 4)
void bin_edges_kernel(const float* __restrict__ binary,
                      const float* __restrict__ bcw,
                      const int* __restrict__ index1,
                      const int* __restrict__ index2,
                      const float* __restrict__ u_lo,
                      float* __restrict__ out_b,       // [n_edges*4]
                      unsigned* __restrict__ cursor,   // [T], zeroed
                      unsigned short* __restrict__ ids,// [T*cap]
                      uint4* __restrict__ dvals,       // [T*cap]
                      float* __restrict__ out_u,       // overflow path only
                      int n_edges, int T, int cap, int chunk) {
    __shared__ unsigned hist[MAXB];
    int tid = threadIdx.x;
    for (int t = tid; t < T; t += BT) hist[t] = 0u;
    __syncthreads();

    int e0 = blockIdx.x * chunk;
    int e1 = e0 + chunk; if (e1 > n_edges) e1 = n_edges;

    // pass 1: local histogram
    for (int e = e0 + tid; e < e1; e += BT) {
        unsigned t1 = ((unsigned)index1[e]) >> TILE_SHIFT;
        unsigned t2 = ((unsigned)index2[e]) >> TILE_SHIFT;
        atomicAdd(&hist[t1], 1u);
        atomicAdd(&hist[t2], 1u);
    }
    __syncthreads();

    // reserve ranges: one global atomic per (block, nonzero bin)
    for (int t = tid; t < T; t += BT) {
        unsigned c = hist[t];
        unsigned base = 0u;
        if (c) base = atomicAdd(&cursor[t], c);
        hist[t] = base;   // becomes the LDS slot cursor
    }
    __syncthreads();

    float w[NC];
#pragma unroll
    for (int i = 0; i < NC; ++i) w[i] = bcw[i];

    // pass 2: compute clause deltas, write out_b, scatter payloads
    for (int e = e0 + tid; e < e1; e += BT) {
        int i1 = index1[e];
        int i2 = index2[e];
        float4 bv = ((const float4*)binary)[e];
        float b[4] = {bv.x, bv.y, bv.z, bv.w};

        const float4* p1 = (const float4*)(u_lo + (size_t)i1 * 8);
        float4 a0 = p1[0], a1 = p1[1];
        const float4* p2 = (const float4*)(u_lo + (size_t)i2 * 8);
        float4 c0 = p2[0], c1 = p2[1];
        float u1[8] = {a0.x,a0.y,a0.z,a0.w,a1.x,a1.y,a1.z,a1.w};
        float u2[8] = {c0.x,c0.y,c0.z,c0.w,c1.x,c1.y,c1.z,c1.w};

        float d1[8], d2[8], dbp[4] = {0.f,0.f,0.f,0.f};
#pragma unroll
        for (int i = 0; i < NC; ++i) {
            float a = -u1[i], bb = b[i & 3], c = u2[i];
            float m = fmaxf(a, fmaxf(bb, c));
            float e0x = __expf(a - m);
            float e1x = __expf(bb - m);
            float e2x = __expf(c - m);
            float inv = 1.0f / (e0x + e1x + e2x);
            d1[i] = -w[i] * e0x * inv;
            d2[i] =  w[i] * e2x * inv;
            dbp[i & 3] += w[i] * e1x * inv;
        }
        float4 ob;
        ob.x = b[0] + dbp[0];
        ob.y = b[1] + dbp[1];
        ob.z = b[2] + dbp[2];
        ob.w = b[3] + dbp[3];
        ((float4*)out_b)[e] = ob;

        unsigned t1 = ((unsigned)i1) >> TILE_SHIFT;
        unsigned slot1 = atomicAdd(&hist[t1], 1u);
        if (slot1 < (unsigned)cap) {
            size_t p = (size_t)t1 * cap + slot1;
            ids[p] = (unsigned short)(i1 & (TILE_N - 1));
            uint4 v;
            v.x = (unsigned)f2bf(d1[0]) | ((unsigned)f2bf(d1[1]) << 16);
            v.y = (unsigned)f2bf(d1[2]) | ((unsigned)f2bf(d1[3]) << 16);
            v.z = (unsigned)f2bf(d1[4]) | ((unsigned)f2bf(d1[5]) << 16);
            v.w = (unsigned)f2bf(d1[6]) | ((unsigned)f2bf(d1[7]) << 16);
            dvals[p] = v;
        } else {
            float* r = out_u + (size_t)i1 * NU;
#pragma unroll
            for (int i = 0; i < NC; ++i) atomicAdd(r + i, d1[i]);
        }

        unsigned t2 = ((unsigned)i2) >> TILE_SHIFT;
        unsigned slot2 = atomicAdd(&hist[t2], 1u);
        if (slot2 < (unsigned)cap) {
            size_t p = (size_t)t2 * cap + slot2;
            ids[p] = (unsigned short)(i2 & (TILE_N - 1));
            uint4 v;
            v.x = (unsigned)f2bf(d2[0]) | ((unsigned)f2bf(d2[1]) << 16);
            v.y = (unsigned)f2bf(d2[2]) | ((unsigned)f2bf(d2[3]) << 16);
            v.z = (unsigned)f2bf(d2[4]) | ((unsigned)f2bf(d2[5]) << 16);
            v.w = (unsigned)f2bf(d2[6]) | ((unsigned)f2bf(d2[7]) << 16);
            dvals[p] = v;
        } else {
            float* r = out_u + (size_t)i2 * NU;
#pragma unroll
            for (int i = 0; i < NC; ++i) atomicAdd(r + i, d2[i]);
        }
    }
}

// Accumulate pass: column-major LDS acc (bank = id%32, conflict-free),
// 4 entries per thread per iteration for memory-level parallelism.
__global__ __launch_bounds__(256, 4)
void tile_acc_kernel(const unsigned* __restrict__ cursor,
                     const unsigned short* __restrict__ ids,
                     const uint4* __restrict__ dvals,
                     float* __restrict__ out_u,
                     int n_nodes, int cap) {
    __shared__ float acc[8 * TILE_N];   // acc[j*TILE_N + id]
    int t = blockIdx.x;
    int tid = threadIdx.x;
    for (int i = tid; i < 8 * TILE_N; i += 256) acc[i] = 0.0f;
    __syncthreads();

    unsigned cnt = cursor[t];
    if (cnt > (unsigned)cap) cnt = (unsigned)cap;
    size_t base = (size_t)t * cap;

    unsigned cnt4 = cnt & ~3u;
    for (unsigned i = (unsigned)tid * 4; i < cnt4; i += 256 * 4) {
        ushort4 idv = *(const ushort4*)(ids + base + i);   // cap%4==0 -> aligned
        uint4 v0 = dvals[base + i + 0];
        uint4 v1 = dvals[base + i + 1];
        uint4 v2 = dvals[base + i + 2];
        uint4 v3 = dvals[base + i + 3];
        unsigned id0 = idv.x, id1 = idv.y, id2 = idv.z, id3 = idv.w;
        uint4 vv[4] = {v0, v1, v2, v3};
        unsigned idk[4] = {id0, id1, id2, id3};
#pragma unroll
        for (int k = 0; k < 4; ++k) {
            unsigned id = idk[k];
            uint4 v = vv[k];
            atomicAdd(&acc[0*TILE_N + id], bf2f(v.x & 0xffffu));
            atomicAdd(&acc[1*TILE_N + id], bf2f(v.x >> 16));
            atomicAdd(&acc[2*TILE_N + id], bf2f(v.y & 0xffffu));
            atomicAdd(&acc[3*TILE_N + id], bf2f(v.y >> 16));
            atomicAdd(&acc[4*TILE_N + id], bf2f(v.z & 0xffffu));
            atomicAdd(&acc[5*TILE_N + id], bf2f(v.z >> 16));
            atomicAdd(&acc[6*TILE_N + id], bf2f(v.w & 0xffffu));
            atomicAdd(&acc[7*TILE_N + id], bf2f(v.w >> 16));
        }
    }
    // tail
    for (unsigned i = cnt4 + tid; i < cnt; i += 256) {
        unsigned id = ids[base + i];
        uint4 v = dvals[base + i];
        atomicAdd(&acc[0*TILE_N + id], bf2f(v.x & 0xffffu));
        atomicAdd(&acc[1*TILE_N + id], bf2f(v.x >> 16));
        atomicAdd(&acc[2*TILE_N + id], bf2f(v.y & 0xffffu));
        atomicAdd(&acc[3*TILE_N + id], bf2f(v.y >> 16));
        atomicAdd(&acc[4*TILE_N + id], bf2f(v.z & 0xffffu));
        atomicAdd(&acc[5*TILE_N + id], bf2f(v.z >> 16));
        atomicAdd(&acc[6*TILE_N + id], bf2f(v.w & 0xffffu));
        atomicAdd(&acc[7*TILE_N + id], bf2f(v.w >> 16));
    }
    __syncthreads();

    int nbase = t << TILE_SHIFT;
    for (int l = tid; l < TILE_N; l += 256) {
        int n = nbase + l;
        if (n >= n_nodes) continue;
        float4* row = (float4*)(out_u + (size_t)n * NU);
        float4 r0 = row[0], r1 = row[1];
        r0.x += acc[0*TILE_N + l]; r0.y += acc[1*TILE_N + l];
        r0.z += acc[2*TILE_N + l]; r0.w += acc[3*TILE_N + l];
        r1.x += acc[4*TILE_N + l]; r1.y += acc[5*TILE_N + l];
        r1.z += acc[6*TILE_N + l]; r1.w += acc[7*TILE_N + l];
        row[0] = r0; row[1] = r1;
    }
}

// Fallback (R1): device-scope atomics, needs only u_lo in ws.
__global__ void edge_enhance_kernel(const float* __restrict__ binary,
                                    const float* __restrict__ bcw,
                                    const int* __restrict__ index1,
                                    const int* __restrict__ index2,
                                    const float* __restrict__ u_lo,
                                    float* __restrict__ out_u,
                                    float* __restrict__ out_b,
                                    int n_edges) {
    int e = blockIdx.x * blockDim.x + threadIdx.x;
    if (e >= n_edges) return;

    int i1 = index1[e];
    int i2 = index2[e];
    float4 bv = ((const float4*)binary)[e];
    float b[4] = {bv.x, bv.y, bv.z, bv.w};

    const float4* p1 = (const float4*)(u_lo + (size_t)i1 * 8);
    float4 a0 = p1[0], a1 = p1[1];
    const float4* p2 = (const float4*)(u_lo + (size_t)i2 * 8);
    float4 c0 = p2[0], c1 = p2[1];
    float u1[8] = {a0.x,a0.y,a0.z,a0.w,a1.x,a1.y,a1.z,a1.w};
    float u2[8] = {c0.x,c0.y,c0.z,c0.w,c1.x,c1.y,c1.z,c1.w};

    float d1[8], d2[8], dbp[4] = {0.f,0.f,0.f,0.f};
#pragma unroll
    for (int i = 0; i < NC; ++i) {
        float w = bcw[i];
        float a = -u1[i], bb = b[i & 3], c = u2[i];
        float m = fmaxf(a, fmaxf(bb, c));
        float e0 = __expf(a - m);
        float e1 = __expf(bb - m);
        float e2 = __expf(c - m);
        float inv = 1.0f / (e0 + e1 + e2);
        d1[i] = -w * e0 * inv;
        d2[i] =  w * e2 * inv;
        dbp[i & 3] += w * e1 * inv;
    }
    float* r1 = out_u + (size_t)i1 * NU;
#pragma unroll
    for (int i = 0; i < NC; ++i) atomicAdd(r1 + i, d1[i]);
    float* r2 = out_u + (size_t)i2 * NU;
#pragma unroll
    for (int i = 0; i < NC; ++i) atomicAdd(r2 + i, d2[i]);

    float4 ob;
    ob.x = b[0] + dbp[0];
    ob.y = b[1] + dbp[1];
    ob.z = b[2] + dbp[2];
    ob.w = b[3] + dbp[3];
    ((float4*)out_b)[e] = ob;
}

extern "C" void kernel_launch(void* const* d_in, const int* in_sizes, int n_in,
                              void* d_out, int out_size, void* d_ws, size_t ws_size,
                              hipStream_t stream) {
    const float* unary  = (const float*)d_in[0];
    const float* binary = (const float*)d_in[1];
    const float* ucw    = (const float*)d_in[2];
    const float* bcw    = (const float*)d_in[3];
    const int*   index1 = (const int*)d_in[4];
    const int*   index2 = (const int*)d_in[5];

    int n_nodes = in_sizes[0] / NU;
    int n_edges = in_sizes[4];

    float* out_u = (float*)d_out;
    float* out_b = out_u + (size_t)n_nodes * NU;

    int T = (n_nodes + TILE_N - 1) >> TILE_SHIFT;
    size_t mean = (2ull * (size_t)n_edges) / (size_t)T;
    int cap = (int)(mean + mean / 8 + 512);
    cap = (cap + 3) & ~3;   // ushort4 alignment in tile_acc

    // ws layout: u_lo [n_nodes*8 f32] | dvals [T*cap uint4] | ids [T*cap u16] | cursor [T u32]
    size_t u_lo_bytes  = (size_t)n_nodes * 8 * sizeof(float);
    size_t dvals_off   = (u_lo_bytes + 15) & ~(size_t)15;
    size_t dvals_bytes = (size_t)T * cap * sizeof(uint4);
    size_t ids_off     = dvals_off + dvals_bytes;
    size_t ids_bytes   = ((size_t)T * cap * 2 + 3) & ~(size_t)3;
    size_t cur_off     = ids_off + ids_bytes;
    size_t cur_bytes   = (size_t)T * 4;
    size_t need        = cur_off + cur_bytes;

    float* u_lo = (float*)d_ws;
    uint4* dvals = (uint4*)((char*)d_ws + dvals_off);
    unsigned short* ids = (unsigned short*)((char*)d_ws + ids_off);
    unsigned* cursor = (unsigned*)((char*)d_ws + cur_off);

    int tb = 256;
    unary_enhance_kernel<<<(n_nodes + tb - 1) / tb, tb, 0, stream>>>(
        unary, ucw, out_u, u_lo, n_nodes);

    if (ws_size >= need && T <= MAXB) {
        hipMemsetAsync(cursor, 0, cur_bytes, stream);
        int chunk = (n_edges + NB - 1) / NB;
        bin_edges_kernel<<<NB, BT, 0, stream>>>(
            binary, bcw, index1, index2, u_lo, out_b,
            cursor, ids, dvals, out_u, n_edges, T, cap, chunk);
        tile_acc_kernel<<<T, 256, 0, stream>>>(
            cursor, ids, dvals, out_u, n_nodes, cap);
    } else {
        edge_enhance_kernel<<<(n_edges + tb - 1) / tb, tb, 0, stream>>>(
            binary, bcw, index1, index2, u_lo, out_u, out_b, n_edges);
    }
}

// Round 7
// 283.468 us; speedup vs baseline: 4.8892x; 1.5073x over previous
//
#include <hip/hip_runtime.h>
#include <math.h>

// RelationalKENN R7 (R6 retry): test H = tile_acc bound by LDS atomic OP COUNT.
// R4 (16 scalar-iter loop) and R5 (4x vectorized, bank-conflict-free) both hit
// exactly 172us with the same 8 ds_add_f32 per entry -> op count is the invariant.
// Now: 4x ds_add_u64 per entry. Columns packed pairwise as 64-bit fixed point:
// addend = ((u64)(u32)round(d_hi*2^20) << 32) + sext64(round(d_lo*2^20)).
// Low/high sums recovered exactly: s1 += (s0 < 0). Quantization ~3e-5.

#define NU 16
#define NC 8
#define TILE_N 128
#define TILE_SHIFT 7
#define ACC_STRIDE 132   // u64 stride; bank-pair = (4c+id)%16 spread
#define NB 512        // bin-pass blocks
#define BT 512        // bin-pass block size
#define MAXB 1024     // max tiles supported by LDS histogram

__device__ __forceinline__ unsigned short f2bf(float x) {
    unsigned b = __float_as_uint(x);
    unsigned r = (b + 0x7fffu + ((b >> 16) & 1u)) >> 16;
    return (unsigned short)r;
}
__device__ __forceinline__ float bf2f(unsigned h) {
    return __uint_as_float(h << 16);
}
__device__ __forceinline__ unsigned long long pack2fx(float lo, float hi) {
    int a0 = __float2int_rn(lo * 1048576.0f);   // 2^20
    int a1 = __float2int_rn(hi * 1048576.0f);
    return ((unsigned long long)(unsigned)a1 << 32) +
           (unsigned long long)(long long)a0;    // sext low into 64b
}

__global__ void unary_enhance_kernel(const float* __restrict__ unary,
                                     const float* __restrict__ ucw,
                                     float* __restrict__ out_u,   // [n_nodes*16]
                                     float* __restrict__ u_lo,    // [n_nodes*8]
                                     int n_nodes) {
    int n = blockIdx.x * blockDim.x + threadIdx.x;
    if (n >= n_nodes) return;

    float x[NU];
    const float4* src = (const float4*)(unary + (size_t)n * NU);
#pragma unroll
    for (int j = 0; j < 4; ++j) {
        float4 v = src[j];
        x[4*j+0] = v.x; x[4*j+1] = v.y; x[4*j+2] = v.z; x[4*j+3] = v.w;
    }
    float dlt[NU];
#pragma unroll
    for (int j = 0; j < NU; ++j) dlt[j] = 0.0f;
#pragma unroll
    for (int i = 0; i < NC; ++i) {
        float w = ucw[i];
        float a = -x[i], b = x[i+1], c = x[i+2];
        float m = fmaxf(a, fmaxf(b, c));
        float e0 = __expf(a - m);
        float e1 = __expf(b - m);
        float e2 = __expf(c - m);
        float inv = 1.0f / (e0 + e1 + e2);
        dlt[i]   -= w * e0 * inv;
        dlt[i+1] += w * e1 * inv;
        dlt[i+2] += w * e2 * inv;
    }
    float u[NU];
#pragma unroll
    for (int j = 0; j < NU; ++j) u[j] = x[j] + dlt[j];

    float4* dst = (float4*)(out_u + (size_t)n * NU);
#pragma unroll
    for (int j = 0; j < 4; ++j) {
        float4 v; v.x = u[4*j+0]; v.y = u[4*j+1]; v.z = u[4*j+2]; v.w = u[4*j+3];
        dst[j] = v;
    }
    float4* lo = (float4*)(u_lo + (size_t)n * 8);
    float4 l0; l0.x = u[0]; l0.y = u[1]; l0.z = u[2]; l0.w = u[3];
    float4 l1; l1.x = u[4]; l1.y = u[5]; l1.z = u[6]; l1.w = u[7];
    lo[0] = l0; lo[1] = l1;
}

__global__ __launch_bounds__(BT, 4)
void bin_edges_kernel(const float* __restrict__ binary,
                      const float* __restrict__ bcw,
                      const int* __restrict__ index1,
                      const int* __restrict__ index2,
                      const float* __restrict__ u_lo,
                      float* __restrict__ out_b,       // [n_edges*4]
                      unsigned* __restrict__ cursor,   // [T], zeroed
                      unsigned short* __restrict__ ids,// [T*cap]
                      uint4* __restrict__ dvals,       // [T*cap]
                      float* __restrict__ out_u,       // overflow path only
                      int n_edges, int T, int cap, int chunk) {
    __shared__ unsigned hist[MAXB];
    int tid = threadIdx.x;
    for (int t = tid; t < T; t += BT) hist[t] = 0u;
    __syncthreads();

    int e0 = blockIdx.x * chunk;
    int e1 = e0 + chunk; if (e1 > n_edges) e1 = n_edges;

    // pass 1: local histogram
    for (int e = e0 + tid; e < e1; e += BT) {
        unsigned t1 = ((unsigned)index1[e]) >> TILE_SHIFT;
        unsigned t2 = ((unsigned)index2[e]) >> TILE_SHIFT;
        atomicAdd(&hist[t1], 1u);
        atomicAdd(&hist[t2], 1u);
    }
    __syncthreads();

    // reserve ranges: one global atomic per (block, nonzero bin)
    for (int t = tid; t < T; t += BT) {
        unsigned c = hist[t];
        unsigned base = 0u;
        if (c) base = atomicAdd(&cursor[t], c);
        hist[t] = base;   // becomes the LDS slot cursor
    }
    __syncthreads();

    float w[NC];
#pragma unroll
    for (int i = 0; i < NC; ++i) w[i] = bcw[i];

    // pass 2: compute clause deltas, write out_b, scatter payloads
    for (int e = e0 + tid; e < e1; e += BT) {
        int i1 = index1[e];
        int i2 = index2[e];
        float4 bv = ((const float4*)binary)[e];
        float b[4] = {bv.x, bv.y, bv.z, bv.w};

        const float4* p1 = (const float4*)(u_lo + (size_t)i1 * 8);
        float4 a0 = p1[0], a1 = p1[1];
        const float4* p2 = (const float4*)(u_lo + (size_t)i2 * 8);
        float4 c0 = p2[0], c1 = p2[1];
        float u1[8] = {a0.x,a0.y,a0.z,a0.w,a1.x,a1.y,a1.z,a1.w};
        float u2[8] = {c0.x,c0.y,c0.z,c0.w,c1.x,c1.y,c1.z,c1.w};

        float d1[8], d2[8], dbp[4] = {0.f,0.f,0.f,0.f};
#pragma unroll
        for (int i = 0; i < NC; ++i) {
            float a = -u1[i], bb = b[i & 3], c = u2[i];
            float m = fmaxf(a, fmaxf(bb, c));
            float e0x = __expf(a - m);
            float e1x = __expf(bb - m);
            float e2x = __expf(c - m);
            float inv = 1.0f / (e0x + e1x + e2x);
            d1[i] = -w[i] * e0x * inv;
            d2[i] =  w[i] * e2x * inv;
            dbp[i & 3] += w[i] * e1x * inv;
        }
        float4 ob;
        ob.x = b[0] + dbp[0];
        ob.y = b[1] + dbp[1];
        ob.z = b[2] + dbp[2];
        ob.w = b[3] + dbp[3];
        ((float4*)out_b)[e] = ob;

        unsigned t1 = ((unsigned)i1) >> TILE_SHIFT;
        unsigned slot1 = atomicAdd(&hist[t1], 1u);
        if (slot1 < (unsigned)cap) {
            size_t p = (size_t)t1 * cap + slot1;
            ids[p] = (unsigned short)(i1 & (TILE_N - 1));
            uint4 v;
            v.x = (unsigned)f2bf(d1[0]) | ((unsigned)f2bf(d1[1]) << 16);
            v.y = (unsigned)f2bf(d1[2]) | ((unsigned)f2bf(d1[3]) << 16);
            v.z = (unsigned)f2bf(d1[4]) | ((unsigned)f2bf(d1[5]) << 16);
            v.w = (unsigned)f2bf(d1[6]) | ((unsigned)f2bf(d1[7]) << 16);
            dvals[p] = v;
        } else {
            float* r = out_u + (size_t)i1 * NU;
#pragma unroll
            for (int i = 0; i < NC; ++i) atomicAdd(r + i, d1[i]);
        }

        unsigned t2 = ((unsigned)i2) >> TILE_SHIFT;
        unsigned slot2 = atomicAdd(&hist[t2], 1u);
        if (slot2 < (unsigned)cap) {
            size_t p = (size_t)t2 * cap + slot2;
            ids[p] = (unsigned short)(i2 & (TILE_N - 1));
            uint4 v;
            v.x = (unsigned)f2bf(d2[0]) | ((unsigned)f2bf(d2[1]) << 16);
            v.y = (unsigned)f2bf(d2[2]) | ((unsigned)f2bf(d2[3]) << 16);
            v.z = (unsigned)f2bf(d2[4]) | ((unsigned)f2bf(d2[5]) << 16);
            v.w = (unsigned)f2bf(d2[6]) | ((unsigned)f2bf(d2[7]) << 16);
            dvals[p] = v;
        } else {
            float* r = out_u + (size_t)i2 * NU;
#pragma unroll
            for (int i = 0; i < NC; ++i) atomicAdd(r + i, d2[i]);
        }
    }
}

// Accumulate pass: 4x ds_add_u64 per entry (column pairs in 64-bit fixed point).
__global__ __launch_bounds__(256, 4)
void tile_acc_kernel(const unsigned* __restrict__ cursor,
                     const unsigned short* __restrict__ ids,
                     const uint4* __restrict__ dvals,
                     float* __restrict__ out_u,
                     int n_nodes, int cap) {
    __shared__ unsigned long long acc[4 * ACC_STRIDE];  // acc[c*ACC_STRIDE + id]
    int t = blockIdx.x;
    int tid = threadIdx.x;
    for (int i = tid; i < 4 * ACC_STRIDE; i += 256) acc[i] = 0ull;
    __syncthreads();

    unsigned cnt = cursor[t];
    if (cnt > (unsigned)cap) cnt = (unsigned)cap;
    size_t base = (size_t)t * cap;

    unsigned cnt4 = cnt & ~3u;
    for (unsigned i = (unsigned)tid * 4; i < cnt4; i += 256 * 4) {
        ushort4 idv = *(const ushort4*)(ids + base + i);   // cap%4==0 -> aligned
        uint4 v0 = dvals[base + i + 0];
        uint4 v1 = dvals[base + i + 1];
        uint4 v2 = dvals[base + i + 2];
        uint4 v3 = dvals[base + i + 3];
        uint4 vv[4] = {v0, v1, v2, v3};
        unsigned idk[4] = {idv.x, idv.y, idv.z, idv.w};
#pragma unroll
        for (int k = 0; k < 4; ++k) {
            unsigned id = idk[k];
            uint4 v = vv[k];
            atomicAdd(&acc[0*ACC_STRIDE + id], pack2fx(bf2f(v.x & 0xffffu), bf2f(v.x >> 16)));
            atomicAdd(&acc[1*ACC_STRIDE + id], pack2fx(bf2f(v.y & 0xffffu), bf2f(v.y >> 16)));
            atomicAdd(&acc[2*ACC_STRIDE + id], pack2fx(bf2f(v.z & 0xffffu), bf2f(v.z >> 16)));
            atomicAdd(&acc[3*ACC_STRIDE + id], pack2fx(bf2f(v.w & 0xffffu), bf2f(v.w >> 16)));
        }
    }
    // tail
    for (unsigned i = cnt4 + tid; i < cnt; i += 256) {
        unsigned id = ids[base + i];
        uint4 v = dvals[base + i];
        atomicAdd(&acc[0*ACC_STRIDE + id], pack2fx(bf2f(v.x & 0xffffu), bf2f(v.x >> 16)));
        atomicAdd(&acc[1*ACC_STRIDE + id], pack2fx(bf2f(v.y & 0xffffu), bf2f(v.y >> 16)));
        atomicAdd(&acc[2*ACC_STRIDE + id], pack2fx(bf2f(v.z & 0xffffu), bf2f(v.z >> 16)));
        atomicAdd(&acc[3*ACC_STRIDE + id], pack2fx(bf2f(v.w & 0xffffu), bf2f(v.w >> 16)));
    }
    __syncthreads();

    const float INV = 1.0f / 1048576.0f;
    int nbase = t << TILE_SHIFT;
    for (int l = tid; l < TILE_N; l += 256) {
        int n = nbase + l;
        if (n >= n_nodes) continue;
        float col[8];
#pragma unroll
        for (int c = 0; c < 4; ++c) {
            unsigned long long s = acc[c*ACC_STRIDE + l];
            int s0 = (int)(unsigned)(s & 0xffffffffull);
            int s1 = (int)(unsigned)(s >> 32);
            if (s0 < 0) s1 += 1;     // exact split-sum recovery
            col[2*c]   = (float)s0 * INV;
            col[2*c+1] = (float)s1 * INV;
        }
        float4* row = (float4*)(out_u + (size_t)n * NU);
        float4 r0 = row[0], r1 = row[1];
        r0.x += col[0]; r0.y += col[1]; r0.z += col[2]; r0.w += col[3];
        r1.x += col[4]; r1.y += col[5]; r1.z += col[6]; r1.w += col[7];
        row[0] = r0; row[1] = r1;
    }
}

// Fallback (R1): device-scope atomics, needs only u_lo in ws.
__global__ void edge_enhance_kernel(const float* __restrict__ binary,
                                    const float* __restrict__ bcw,
                                    const int* __restrict__ index1,
                                    const int* __restrict__ index2,
                                    const float* __restrict__ u_lo,
                                    float* __restrict__ out_u,
                                    float* __restrict__ out_b,
                                    int n_edges) {
    int e = blockIdx.x * blockDim.x + threadIdx.x;
    if (e >= n_edges) return;

    int i1 = index1[e];
    int i2 = index2[e];
    float4 bv = ((const float4*)binary)[e];
    float b[4] = {bv.x, bv.y, bv.z, bv.w};

    const float4* p1 = (const float4*)(u_lo + (size_t)i1 * 8);
    float4 a0 = p1[0], a1 = p1[1];
    const float4* p2 = (const float4*)(u_lo + (size_t)i2 * 8);
    float4 c0 = p2[0], c1 = p2[1];
    float u1[8] = {a0.x,a0.y,a0.z,a0.w,a1.x,a1.y,a1.z,a1.w};
    float u2[8] = {c0.x,c0.y,c0.z,c0.w,c1.x,c1.y,c1.z,c1.w};

    float d1[8], d2[8], dbp[4] = {0.f,0.f,0.f,0.f};
#pragma unroll
    for (int i = 0; i < NC; ++i) {
        float w = bcw[i];
        float a = -u1[i], bb = b[i & 3], c = u2[i];
        float m = fmaxf(a, fmaxf(bb, c));
        float e0 = __expf(a - m);
        float e1 = __expf(bb - m);
        float e2 = __expf(c - m);
        float inv = 1.0f / (e0 + e1 + e2);
        d1[i] = -w * e0 * inv;
        d2[i] =  w * e2 * inv;
        dbp[i & 3] += w * e1 * inv;
    }
    float* r1 = out_u + (size_t)i1 * NU;
#pragma unroll
    for (int i = 0; i < NC; ++i) atomicAdd(r1 + i, d1[i]);
    float* r2 = out_u + (size_t)i2 * NU;
#pragma unroll
    for (int i = 0; i < NC; ++i) atomicAdd(r2 + i, d2[i]);

    float4 ob;
    ob.x = b[0] + dbp[0];
    ob.y = b[1] + dbp[1];
    ob.z = b[2] + dbp[2];
    ob.w = b[3] + dbp[3];
    ((float4*)out_b)[e] = ob;
}

extern "C" void kernel_launch(void* const* d_in, const int* in_sizes, int n_in,
                              void* d_out, int out_size, void* d_ws, size_t ws_size,
                              hipStream_t stream) {
    const float* unary  = (const float*)d_in[0];
    const float* binary = (const float*)d_in[1];
    const float* ucw    = (const float*)d_in[2];
    const float* bcw    = (const float*)d_in[3];
    const int*   index1 = (const int*)d_in[4];
    const int*   index2 = (const int*)d_in[5];

    int n_nodes = in_sizes[0] / NU;
    int n_edges = in_sizes[4];

    float* out_u = (float*)d_out;
    float* out_b = out_u + (size_t)n_nodes * NU;

    int T = (n_nodes + TILE_N - 1) >> TILE_SHIFT;
    size_t mean = (2ull * (size_t)n_edges) / (size_t)T;
    int cap = (int)(mean + mean / 8 + 512);
    cap = (cap + 3) & ~3;   // ushort4 alignment in tile_acc

    // ws layout: u_lo [n_nodes*8 f32] | dvals [T*cap uint4] | ids [T*cap u16] | cursor [T u32]
    size_t u_lo_bytes  = (size_t)n_nodes * 8 * sizeof(float);
    size_t dvals_off   = (u_lo_bytes + 15) & ~(size_t)15;
    size_t dvals_bytes = (size_t)T * cap * sizeof(uint4);
    size_t ids_off     = dvals_off + dvals_bytes;
    size_t ids_bytes   = ((size_t)T * cap * 2 + 3) & ~(size_t)3;
    size_t cur_off     = ids_off + ids_bytes;
    size_t cur_bytes   = (size_t)T * 4;
    size_t need        = cur_off + cur_bytes;

    float* u_lo = (float*)d_ws;
    uint4* dvals = (uint4*)((char*)d_ws + dvals_off);
    unsigned short* ids = (unsigned short*)((char*)d_ws + ids_off);
    unsigned* cursor = (unsigned*)((char*)d_ws + cur_off);

    int tb = 256;
    unary_enhance_kernel<<<(n_nodes + tb - 1) / tb, tb, 0, stream>>>(
        unary, ucw, out_u, u_lo, n_nodes);

    if (ws_size >= need && T <= MAXB) {
        (void)hipMemsetAsync(cursor, 0, cur_bytes, stream);
        int chunk = (n_edges + NB - 1) / NB;
        bin_edges_kernel<<<NB, BT, 0, stream>>>(
            binary, bcw, index1, index2, u_lo, out_b,
            cursor, ids, dvals, out_u, n_edges, T, cap, chunk);
        tile_acc_kernel<<<T, 256, 0, stream>>>(
            cursor, ids, dvals, out_u, n_nodes, cap);
    } else {
        edge_enhance_kernel<<<(n_edges + tb - 1) / tb, tb, 0, stream>>>(
            binary, bcw, index1, index2, u_lo, out_u, out_b, n_edges);
    }
}

// Round 8
// 214.474 us; speedup vs baseline: 6.4621x; 1.3217x over previous
//
#include <hip/hip_runtime.h>
#include <math.h>

// RelationalKENN R8: attack both op-count walls found in R4-R7.
// Facts: LDS atomic lane-ops cost ~4cyc each (R4=R5; R7 halved ops -> halved time);
// bin_edges is occupancy-independent (R4 9.8% = R7 33% = ~176us) -> bound by
// scattered L2 transactions + write-allocate inflation.
// R8: (1) ONE 16B entry per side (8x10-bit fixed @512 + 8-bit id) - no ids array;
// (2) tile_acc: 2x ds_add_u64 per entry (4 cols per u64, 16-bit fields, exact
// sequential-sext recovery); (3) TILE_N=256.

#define NU 16
#define NC 8
#define TILE_N 256
#define TILE_SHIFT 8
#define ACC_ST 257      // u64 stride
#define NB 512
#define BT 512
#define MAXB 1024

__device__ __forceinline__ int q10(float x) {
    int q = __float2int_rn(x * 512.0f);
    q = q < -511 ? -511 : (q > 511 ? 511 : q);
    return q & 0x3FF;
}
__device__ __forceinline__ int sx10(unsigned w, int sh) {  // extract signed 10-bit at sh
    return ((int)(w << (22 - sh))) >> 22;
}
__device__ __forceinline__ unsigned long long pk4(int a0, int a1, int a2, int a3) {
    return (unsigned long long)(long long)a0 +
           ((unsigned long long)(long long)a1 << 16) +
           ((unsigned long long)(long long)a2 << 32) +
           ((unsigned long long)(unsigned short)a3 << 48);
}

__global__ void unary_enhance_kernel(const float* __restrict__ unary,
                                     const float* __restrict__ ucw,
                                     float* __restrict__ out_u,   // [n_nodes*16]
                                     float* __restrict__ u_lo,    // [n_nodes*8]
                                     int n_nodes) {
    int n = blockIdx.x * blockDim.x + threadIdx.x;
    if (n >= n_nodes) return;

    float x[NU];
    const float4* src = (const float4*)(unary + (size_t)n * NU);
#pragma unroll
    for (int j = 0; j < 4; ++j) {
        float4 v = src[j];
        x[4*j+0] = v.x; x[4*j+1] = v.y; x[4*j+2] = v.z; x[4*j+3] = v.w;
    }
    float dlt[NU];
#pragma unroll
    for (int j = 0; j < NU; ++j) dlt[j] = 0.0f;
#pragma unroll
    for (int i = 0; i < NC; ++i) {
        float w = ucw[i];
        float a = -x[i], b = x[i+1], c = x[i+2];
        float m = fmaxf(a, fmaxf(b, c));
        float e0 = __expf(a - m);
        float e1 = __expf(b - m);
        float e2 = __expf(c - m);
        float inv = 1.0f / (e0 + e1 + e2);
        dlt[i]   -= w * e0 * inv;
        dlt[i+1] += w * e1 * inv;
        dlt[i+2] += w * e2 * inv;
    }
    float u[NU];
#pragma unroll
    for (int j = 0; j < NU; ++j) u[j] = x[j] + dlt[j];

    float4* dst = (float4*)(out_u + (size_t)n * NU);
#pragma unroll
    for (int j = 0; j < 4; ++j) {
        float4 v; v.x = u[4*j+0]; v.y = u[4*j+1]; v.z = u[4*j+2]; v.w = u[4*j+3];
        dst[j] = v;
    }
    float4* lo = (float4*)(u_lo + (size_t)n * 8);
    float4 l0; l0.x = u[0]; l0.y = u[1]; l0.z = u[2]; l0.w = u[3];
    float4 l1; l1.x = u[4]; l1.y = u[5]; l1.z = u[6]; l1.w = u[7];
    lo[0] = l0; lo[1] = l1;
}

__global__ __launch_bounds__(BT, 4)
void bin_edges_kernel(const float* __restrict__ binary,
                      const float* __restrict__ bcw,
                      const int* __restrict__ index1,
                      const int* __restrict__ index2,
                      const float* __restrict__ u_lo,
                      float* __restrict__ out_b,       // [n_edges*4]
                      unsigned* __restrict__ cursor,   // [T], zeroed
                      uint4* __restrict__ entries,     // [T*cap]
                      float* __restrict__ out_u,       // overflow path only
                      int n_edges, int T, int cap, int chunk) {
    __shared__ unsigned hist[MAXB];
    int tid = threadIdx.x;
    for (int t = tid; t < T; t += BT) hist[t] = 0u;
    __syncthreads();

    int e0 = blockIdx.x * chunk;
    int e1 = e0 + chunk; if (e1 > n_edges) e1 = n_edges;

    // pass 1: local histogram
    for (int e = e0 + tid; e < e1; e += BT) {
        unsigned t1 = ((unsigned)index1[e]) >> TILE_SHIFT;
        unsigned t2 = ((unsigned)index2[e]) >> TILE_SHIFT;
        atomicAdd(&hist[t1], 1u);
        atomicAdd(&hist[t2], 1u);
    }
    __syncthreads();

    // reserve ranges: one global atomic per (block, nonzero bin)
    for (int t = tid; t < T; t += BT) {
        unsigned c = hist[t];
        unsigned base = 0u;
        if (c) base = atomicAdd(&cursor[t], c);
        hist[t] = base;
    }
    __syncthreads();

    float w[NC];
#pragma unroll
    for (int i = 0; i < NC; ++i) w[i] = bcw[i];

    // pass 2: compute, write out_b, scatter ONE 16B entry per side
    for (int e = e0 + tid; e < e1; e += BT) {
        int i1 = index1[e];
        int i2 = index2[e];
        float4 bv = ((const float4*)binary)[e];
        float b[4] = {bv.x, bv.y, bv.z, bv.w};

        const float4* p1 = (const float4*)(u_lo + (size_t)i1 * 8);
        float4 a0 = p1[0], a1 = p1[1];
        const float4* p2 = (const float4*)(u_lo + (size_t)i2 * 8);
        float4 c0 = p2[0], c1 = p2[1];
        float u1[8] = {a0.x,a0.y,a0.z,a0.w,a1.x,a1.y,a1.z,a1.w};
        float u2[8] = {c0.x,c0.y,c0.z,c0.w,c1.x,c1.y,c1.z,c1.w};

        float d1[8], d2[8], dbp[4] = {0.f,0.f,0.f,0.f};
#pragma unroll
        for (int i = 0; i < NC; ++i) {
            float a = -u1[i], bb = b[i & 3], c = u2[i];
            float m = fmaxf(a, fmaxf(bb, c));
            float e0x = __expf(a - m);
            float e1x = __expf(bb - m);
            float e2x = __expf(c - m);
            float inv = 1.0f / (e0x + e1x + e2x);
            d1[i] = -w[i] * e0x * inv;
            d2[i] =  w[i] * e2x * inv;
            dbp[i & 3] += w[i] * e1x * inv;
        }
        float4 ob;
        ob.x = b[0] + dbp[0];
        ob.y = b[1] + dbp[1];
        ob.z = b[2] + dbp[2];
        ob.w = b[3] + dbp[3];
        ((float4*)out_b)[e] = ob;

        unsigned t1 = ((unsigned)i1) >> TILE_SHIFT;
        unsigned slot1 = atomicAdd(&hist[t1], 1u);
        if (slot1 < (unsigned)cap) {
            uint4 v;
            v.x = (unsigned)q10(d1[0]) | ((unsigned)q10(d1[1]) << 10) | ((unsigned)q10(d1[2]) << 20);
            v.y = (unsigned)q10(d1[3]) | ((unsigned)q10(d1[4]) << 10) | ((unsigned)q10(d1[5]) << 20);
            v.z = (unsigned)q10(d1[6]) | ((unsigned)q10(d1[7]) << 10) |
                  ((unsigned)(i1 & (TILE_N - 1)) << 20);
            v.w = 0u;
            entries[(size_t)t1 * cap + slot1] = v;
        } else {
            float* r = out_u + (size_t)i1 * NU;
#pragma unroll
            for (int i = 0; i < NC; ++i) atomicAdd(r + i, d1[i]);
        }

        unsigned t2 = ((unsigned)i2) >> TILE_SHIFT;
        unsigned slot2 = atomicAdd(&hist[t2], 1u);
        if (slot2 < (unsigned)cap) {
            uint4 v;
            v.x = (unsigned)q10(d2[0]) | ((unsigned)q10(d2[1]) << 10) | ((unsigned)q10(d2[2]) << 20);
            v.y = (unsigned)q10(d2[3]) | ((unsigned)q10(d2[4]) << 10) | ((unsigned)q10(d2[5]) << 20);
            v.z = (unsigned)q10(d2[6]) | ((unsigned)q10(d2[7]) << 10) |
                  ((unsigned)(i2 & (TILE_N - 1)) << 20);
            v.w = 0u;
            entries[(size_t)t2 * cap + slot2] = v;
        } else {
            float* r = out_u + (size_t)i2 * NU;
#pragma unroll
            for (int i = 0; i < NC; ++i) atomicAdd(r + i, d2[i]);
        }
    }
}

// Accumulate pass: 2x ds_add_u64 per entry (4 cols per u64, 16-bit fields).
__global__ __launch_bounds__(256, 4)
void tile_acc_kernel(const unsigned* __restrict__ cursor,
                     const uint4* __restrict__ entries,
                     float* __restrict__ out_u,
                     int n_nodes, int cap) {
    __shared__ unsigned long long acc[2 * ACC_ST];  // acc[w*ACC_ST + id]
    int t = blockIdx.x;
    int tid = threadIdx.x;
    for (int i = tid; i < 2 * ACC_ST; i += 256) acc[i] = 0ull;
    __syncthreads();

    unsigned cnt = cursor[t];
    if (cnt > (unsigned)cap) cnt = (unsigned)cap;
    size_t base = (size_t)t * cap;

    unsigned cnt4 = cnt & ~3u;
    for (unsigned i = (unsigned)tid * 4; i < cnt4; i += 256 * 4) {
        uint4 v0 = entries[base + i + 0];
        uint4 v1 = entries[base + i + 1];
        uint4 v2 = entries[base + i + 2];
        uint4 v3 = entries[base + i + 3];
        uint4 vv[4] = {v0, v1, v2, v3};
#pragma unroll
        for (int k = 0; k < 4; ++k) {
            uint4 v = vv[k];
            unsigned id = v.z >> 20;
            unsigned long long lo = pk4(sx10(v.x, 0), sx10(v.x, 10), sx10(v.x, 20), sx10(v.y, 0));
            unsigned long long hi = pk4(sx10(v.y, 10), sx10(v.y, 20), sx10(v.z, 0), sx10(v.z, 10));
            atomicAdd(&acc[id], lo);
            atomicAdd(&acc[ACC_ST + id], hi);
        }
    }
    for (unsigned i = cnt4 + tid; i < cnt; i += 256) {
        uint4 v = entries[base + i];
        unsigned id = v.z >> 20;
        unsigned long long lo = pk4(sx10(v.x, 0), sx10(v.x, 10), sx10(v.x, 20), sx10(v.y, 0));
        unsigned long long hi = pk4(sx10(v.y, 10), sx10(v.y, 20), sx10(v.z, 0), sx10(v.z, 10));
        atomicAdd(&acc[id], lo);
        atomicAdd(&acc[ACC_ST + id], hi);
    }
    __syncthreads();

    const float INV = 1.0f / 512.0f;
    int nbase = t << TILE_SHIFT;
    for (int l = tid; l < TILE_N; l += 256) {
        int n = nbase + l;
        if (n >= n_nodes) continue;
        float col[8];
#pragma unroll
        for (int wd = 0; wd < 2; ++wd) {
            unsigned long long S = acc[wd*ACC_ST + l];
#pragma unroll
            for (int f = 0; f < 4; ++f) {
                short s = (short)(S & 0xFFFFull);
                col[wd*4 + f] = (float)s * INV;
                S = (S - (unsigned long long)(long long)s) >> 16;
            }
        }
        float4* row = (float4*)(out_u + (size_t)n * NU);
        float4 r0 = row[0], r1 = row[1];
        r0.x += col[0]; r0.y += col[1]; r0.z += col[2]; r0.w += col[3];
        r1.x += col[4]; r1.y += col[5]; r1.z += col[6]; r1.w += col[7];
        row[0] = r0; row[1] = r1;
    }
}

// Fallback (R1): device-scope atomics, needs only u_lo in ws.
__global__ void edge_enhance_kernel(const float* __restrict__ binary,
                                    const float* __restrict__ bcw,
                                    const int* __restrict__ index1,
                                    const int* __restrict__ index2,
                                    const float* __restrict__ u_lo,
                                    float* __restrict__ out_u,
                                    float* __restrict__ out_b,
                                    int n_edges) {
    int e = blockIdx.x * blockDim.x + threadIdx.x;
    if (e >= n_edges) return;

    int i1 = index1[e];
    int i2 = index2[e];
    float4 bv = ((const float4*)binary)[e];
    float b[4] = {bv.x, bv.y, bv.z, bv.w};

    const float4* p1 = (const float4*)(u_lo + (size_t)i1 * 8);
    float4 a0 = p1[0], a1 = p1[1];
    const float4* p2 = (const float4*)(u_lo + (size_t)i2 * 8);
    float4 c0 = p2[0], c1 = p2[1];
    float u1[8] = {a0.x,a0.y,a0.z,a0.w,a1.x,a1.y,a1.z,a1.w};
    float u2[8] = {c0.x,c0.y,c0.z,c0.w,c1.x,c1.y,c1.z,c1.w};

    float d1[8], d2[8], dbp[4] = {0.f,0.f,0.f,0.f};
#pragma unroll
    for (int i = 0; i < NC; ++i) {
        float w = bcw[i];
        float a = -u1[i], bb = b[i & 3], c = u2[i];
        float m = fmaxf(a, fmaxf(bb, c));
        float e0 = __expf(a - m);
        float e1 = __expf(bb - m);
        float e2 = __expf(c - m);
        float inv = 1.0f / (e0 + e1 + e2);
        d1[i] = -w * e0 * inv;
        d2[i] =  w * e2 * inv;
        dbp[i & 3] += w * e1 * inv;
    }
    float* r1 = out_u + (size_t)i1 * NU;
#pragma unroll
    for (int i = 0; i < NC; ++i) atomicAdd(r1 + i, d1[i]);
    float* r2 = out_u + (size_t)i2 * NU;
#pragma unroll
    for (int i = 0; i < NC; ++i) atomicAdd(r2 + i, d2[i]);

    float4 ob;
    ob.x = b[0] + dbp[0];
    ob.y = b[1] + dbp[1];
    ob.z = b[2] + dbp[2];
    ob.w = b[3] + dbp[3];
    ((float4*)out_b)[e] = ob;
}

extern "C" void kernel_launch(void* const* d_in, const int* in_sizes, int n_in,
                              void* d_out, int out_size, void* d_ws, size_t ws_size,
                              hipStream_t stream) {
    const float* unary  = (const float*)d_in[0];
    const float* binary = (const float*)d_in[1];
    const float* ucw    = (const float*)d_in[2];
    const float* bcw    = (const float*)d_in[3];
    const int*   index1 = (const int*)d_in[4];
    const int*   index2 = (const int*)d_in[5];

    int n_nodes = in_sizes[0] / NU;
    int n_edges = in_sizes[4];

    float* out_u = (float*)d_out;
    float* out_b = out_u + (size_t)n_nodes * NU;

    int T = (n_nodes + TILE_N - 1) >> TILE_SHIFT;
    size_t mean = (2ull * (size_t)n_edges) / (size_t)T;
    int cap = (int)(mean + mean / 8 + 512);
    cap = (cap + 3) & ~3;

    // ws layout: u_lo [n_nodes*8 f32] | entries [T*cap uint4] | cursor [T u32]
    size_t u_lo_bytes  = (size_t)n_nodes * 8 * sizeof(float);
    size_t ent_off     = (u_lo_bytes + 15) & ~(size_t)15;
    size_t ent_bytes   = (size_t)T * cap * sizeof(uint4);
    size_t cur_off     = ent_off + ent_bytes;
    size_t cur_bytes   = (size_t)T * 4;
    size_t need        = cur_off + cur_bytes;

    float* u_lo = (float*)d_ws;
    uint4* entries = (uint4*)((char*)d_ws + ent_off);
    unsigned* cursor = (unsigned*)((char*)d_ws + cur_off);

    int tb = 256;
    unary_enhance_kernel<<<(n_nodes + tb - 1) / tb, tb, 0, stream>>>(
        unary, ucw, out_u, u_lo, n_nodes);

    if (ws_size >= need && T <= MAXB) {
        (void)hipMemsetAsync(cursor, 0, cur_bytes, stream);
        int chunk = (n_edges + NB - 1) / NB;
        bin_edges_kernel<<<NB, BT, 0, stream>>>(
            binary, bcw, index1, index2, u_lo, out_b,
            cursor, entries, out_u, n_edges, T, cap, chunk);
        tile_acc_kernel<<<T, 256, 0, stream>>>(
            cursor, entries, out_u, n_nodes, cap);
    } else {
        edge_enhance_kernel<<<(n_edges + tb - 1) / tb, tb, 0, stream>>>(
            binary, bcw, index1, index2, u_lo, out_u, out_b, n_edges);
    }
}

// Round 9
// 204.081 us; speedup vs baseline: 6.7911x; 1.0509x over previous
//
#include <hip/hip_runtime.h>
#include <math.h>

// RelationalKENN R9: balance + byte-trim on the R8 structure.
// Model (R4-R8): LDS atomic lane-ops ~4cyc, occupancy/structure independent.
// Floors: bin 4 ops/edge ~42us; acc 2 ops/entry ~43us; ~230MB mixed traffic.
// R9 changes: T=250 tiles (TILE_N=400) -> tile_acc runs one balanced round
// (R8's T=391 forced 2 sequential rounds on half the CUs); bin pass2 reads
// indices from an LDS cache filled in pass1 (saves 12.8MB re-read + latency).

#define NU 16
#define NC 8
#define TILE_N 400u
#define NB 512        // bin-pass blocks
#define BT 512        // bin-pass block size
#define CACHE_N 3200  // max edges cached per bin block
#define ACC_ST 400

__device__ __forceinline__ int q10(float x) {
    int q = __float2int_rn(x * 512.0f);
    q = q < -511 ? -511 : (q > 511 ? 511 : q);
    return q & 0x3FF;
}
__device__ __forceinline__ int sx10(unsigned w, int sh) {
    return ((int)(w << (22 - sh))) >> 22;
}
__device__ __forceinline__ unsigned long long pk4(int a0, int a1, int a2, int a3) {
    return (unsigned long long)(long long)a0 +
           ((unsigned long long)(long long)a1 << 16) +
           ((unsigned long long)(long long)a2 << 32) +
           ((unsigned long long)(unsigned short)a3 << 48);
}

__global__ void unary_enhance_kernel(const float* __restrict__ unary,
                                     const float* __restrict__ ucw,
                                     float* __restrict__ out_u,   // [n_nodes*16]
                                     float* __restrict__ u_lo,    // [n_nodes*8]
                                     int n_nodes) {
    int n = blockIdx.x * blockDim.x + threadIdx.x;
    if (n >= n_nodes) return;

    float x[NU];
    const float4* src = (const float4*)(unary + (size_t)n * NU);
#pragma unroll
    for (int j = 0; j < 4; ++j) {
        float4 v = src[j];
        x[4*j+0] = v.x; x[4*j+1] = v.y; x[4*j+2] = v.z; x[4*j+3] = v.w;
    }
    float dlt[NU];
#pragma unroll
    for (int j = 0; j < NU; ++j) dlt[j] = 0.0f;
#pragma unroll
    for (int i = 0; i < NC; ++i) {
        float w = ucw[i];
        float a = -x[i], b = x[i+1], c = x[i+2];
        float m = fmaxf(a, fmaxf(b, c));
        float e0 = __expf(a - m);
        float e1 = __expf(b - m);
        float e2 = __expf(c - m);
        float inv = 1.0f / (e0 + e1 + e2);
        dlt[i]   -= w * e0 * inv;
        dlt[i+1] += w * e1 * inv;
        dlt[i+2] += w * e2 * inv;
    }
    float u[NU];
#pragma unroll
    for (int j = 0; j < NU; ++j) u[j] = x[j] + dlt[j];

    float4* dst = (float4*)(out_u + (size_t)n * NU);
#pragma unroll
    for (int j = 0; j < 4; ++j) {
        float4 v; v.x = u[4*j+0]; v.y = u[4*j+1]; v.z = u[4*j+2]; v.w = u[4*j+3];
        dst[j] = v;
    }
    float4* lo = (float4*)(u_lo + (size_t)n * 8);
    float4 l0; l0.x = u[0]; l0.y = u[1]; l0.z = u[2]; l0.w = u[3];
    float4 l1; l1.x = u[4]; l1.y = u[5]; l1.z = u[6]; l1.w = u[7];
    lo[0] = l0; lo[1] = l1;
}

__global__ __launch_bounds__(BT, 8)
void bin_edges_kernel(const float* __restrict__ binary,
                      const float* __restrict__ bcw,
                      const int* __restrict__ index1,
                      const int* __restrict__ index2,
                      const float* __restrict__ u_lo,
                      float* __restrict__ out_b,       // [n_edges*4]
                      unsigned* __restrict__ cursor,   // [T], zeroed
                      uint4* __restrict__ entries,     // [T*cap]
                      float* __restrict__ out_u,       // overflow path only
                      int n_edges, int T, int cap, int chunk) {
    __shared__ unsigned hist[256];
    __shared__ int ic1[CACHE_N];
    __shared__ int ic2[CACHE_N];
    int tid = threadIdx.x;
    for (int t = tid; t < T; t += BT) hist[t] = 0u;
    __syncthreads();

    int e0 = blockIdx.x * chunk;
    int e1 = e0 + chunk; if (e1 > n_edges) e1 = n_edges;

    // pass 1: cache indices in LDS + local histogram
    for (int e = e0 + tid; e < e1; e += BT) {
        int i1 = index1[e];
        int i2 = index2[e];
        int l = e - e0;
        ic1[l] = i1;
        ic2[l] = i2;
        atomicAdd(&hist[(unsigned)i1 / TILE_N], 1u);
        atomicAdd(&hist[(unsigned)i2 / TILE_N], 1u);
    }
    __syncthreads();

    // reserve ranges: one global atomic per (block, nonzero bin)
    for (int t = tid; t < T; t += BT) {
        unsigned c = hist[t];
        unsigned base = 0u;
        if (c) base = atomicAdd(&cursor[t], c);
        hist[t] = base;
    }
    __syncthreads();

    float w[NC];
#pragma unroll
    for (int i = 0; i < NC; ++i) w[i] = bcw[i];

    // pass 2: compute, write out_b, scatter one 16B entry per side
    for (int e = e0 + tid; e < e1; e += BT) {
        int l = e - e0;
        int i1 = ic1[l];
        int i2 = ic2[l];
        float4 bv = ((const float4*)binary)[e];
        float b[4] = {bv.x, bv.y, bv.z, bv.w};

        const float4* p1 = (const float4*)(u_lo + (size_t)i1 * 8);
        float4 a0 = p1[0], a1 = p1[1];
        const float4* p2 = (const float4*)(u_lo + (size_t)i2 * 8);
        float4 c0 = p2[0], c1 = p2[1];
        float u1[8] = {a0.x,a0.y,a0.z,a0.w,a1.x,a1.y,a1.z,a1.w};
        float u2[8] = {c0.x,c0.y,c0.z,c0.w,c1.x,c1.y,c1.z,c1.w};

        float d1[8], d2[8], dbp[4] = {0.f,0.f,0.f,0.f};
#pragma unroll
        for (int i = 0; i < NC; ++i) {
            float a = -u1[i], bb = b[i & 3], c = u2[i];
            float m = fmaxf(a, fmaxf(bb, c));
            float e0x = __expf(a - m);
            float e1x = __expf(bb - m);
            float e2x = __expf(c - m);
            float inv = 1.0f / (e0x + e1x + e2x);
            d1[i] = -w[i] * e0x * inv;
            d2[i] =  w[i] * e2x * inv;
            dbp[i & 3] += w[i] * e1x * inv;
        }
        float4 ob;
        ob.x = b[0] + dbp[0];
        ob.y = b[1] + dbp[1];
        ob.z = b[2] + dbp[2];
        ob.w = b[3] + dbp[3];
        ((float4*)out_b)[e] = ob;

        unsigned t1 = (unsigned)i1 / TILE_N;
        unsigned id1 = (unsigned)i1 - t1 * TILE_N;
        unsigned slot1 = atomicAdd(&hist[t1], 1u);
        if (slot1 < (unsigned)cap) {
            uint4 v;
            v.x = (unsigned)q10(d1[0]) | ((unsigned)q10(d1[1]) << 10) | ((unsigned)q10(d1[2]) << 20);
            v.y = (unsigned)q10(d1[3]) | ((unsigned)q10(d1[4]) << 10) | ((unsigned)q10(d1[5]) << 20);
            v.z = (unsigned)q10(d1[6]) | ((unsigned)q10(d1[7]) << 10) | (id1 << 20);
            v.w = 0u;
            entries[(size_t)t1 * cap + slot1] = v;
        } else {
            float* r = out_u + (size_t)i1 * NU;
#pragma unroll
            for (int i = 0; i < NC; ++i) atomicAdd(r + i, d1[i]);
        }

        unsigned t2 = (unsigned)i2 / TILE_N;
        unsigned id2 = (unsigned)i2 - t2 * TILE_N;
        unsigned slot2 = atomicAdd(&hist[t2], 1u);
        if (slot2 < (unsigned)cap) {
            uint4 v;
            v.x = (unsigned)q10(d2[0]) | ((unsigned)q10(d2[1]) << 10) | ((unsigned)q10(d2[2]) << 20);
            v.y = (unsigned)q10(d2[3]) | ((unsigned)q10(d2[4]) << 10) | ((unsigned)q10(d2[5]) << 20);
            v.z = (unsigned)q10(d2[6]) | ((unsigned)q10(d2[7]) << 10) | (id2 << 20);
            v.w = 0u;
            entries[(size_t)t2 * cap + slot2] = v;
        } else {
            float* r = out_u + (size_t)i2 * NU;
#pragma unroll
            for (int i = 0; i < NC; ++i) atomicAdd(r + i, d2[i]);
        }
    }
}

// Accumulate pass: 2x ds_add_u64 per entry; T=250 blocks -> 1 balanced round.
__global__ __launch_bounds__(512, 4)
void tile_acc_kernel(const unsigned* __restrict__ cursor,
                     const uint4* __restrict__ entries,
                     float* __restrict__ out_u,
                     int n_nodes, int cap) {
    __shared__ unsigned long long acc[2 * ACC_ST];
    int t = blockIdx.x;
    int tid = threadIdx.x;
    for (int i = tid; i < 2 * ACC_ST; i += 512) acc[i] = 0ull;
    __syncthreads();

    unsigned cnt = cursor[t];
    if (cnt > (unsigned)cap) cnt = (unsigned)cap;
    size_t base = (size_t)t * cap;

    unsigned cnt4 = cnt & ~3u;
    for (unsigned i = (unsigned)tid * 4; i < cnt4; i += 512 * 4) {
        uint4 v0 = entries[base + i + 0];
        uint4 v1 = entries[base + i + 1];
        uint4 v2 = entries[base + i + 2];
        uint4 v3 = entries[base + i + 3];
        uint4 vv[4] = {v0, v1, v2, v3};
#pragma unroll
        for (int k = 0; k < 4; ++k) {
            uint4 v = vv[k];
            unsigned id = v.z >> 20;
            unsigned long long lo = pk4(sx10(v.x, 0), sx10(v.x, 10), sx10(v.x, 20), sx10(v.y, 0));
            unsigned long long hi = pk4(sx10(v.y, 10), sx10(v.y, 20), sx10(v.z, 0), sx10(v.z, 10));
            atomicAdd(&acc[id], lo);
            atomicAdd(&acc[ACC_ST + id], hi);
        }
    }
    for (unsigned i = cnt4 + tid; i < cnt; i += 512) {
        uint4 v = entries[base + i];
        unsigned id = v.z >> 20;
        unsigned long long lo = pk4(sx10(v.x, 0), sx10(v.x, 10), sx10(v.x, 20), sx10(v.y, 0));
        unsigned long long hi = pk4(sx10(v.y, 10), sx10(v.y, 20), sx10(v.z, 0), sx10(v.z, 10));
        atomicAdd(&acc[id], lo);
        atomicAdd(&acc[ACC_ST + id], hi);
    }
    __syncthreads();

    const float INV = 1.0f / 512.0f;
    int nbase = t * (int)TILE_N;
    for (int l = tid; l < (int)TILE_N; l += 512) {
        int n = nbase + l;
        if (n >= n_nodes) continue;
        float col[8];
#pragma unroll
        for (int wd = 0; wd < 2; ++wd) {
            unsigned long long S = acc[wd*ACC_ST + l];
#pragma unroll
            for (int f = 0; f < 4; ++f) {
                short s = (short)(S & 0xFFFFull);
                col[wd*4 + f] = (float)s * INV;
                S = (S - (unsigned long long)(long long)s) >> 16;
            }
        }
        float4* row = (float4*)(out_u + (size_t)n * NU);
        float4 r0 = row[0], r1 = row[1];
        r0.x += col[0]; r0.y += col[1]; r0.z += col[2]; r0.w += col[3];
        r1.x += col[4]; r1.y += col[5]; r1.z += col[6]; r1.w += col[7];
        row[0] = r0; row[1] = r1;
    }
}

// Fallback (R1): device-scope atomics, needs only u_lo in ws.
__global__ void edge_enhance_kernel(const float* __restrict__ binary,
                                    const float* __restrict__ bcw,
                                    const int* __restrict__ index1,
                                    const int* __restrict__ index2,
                                    const float* __restrict__ u_lo,
                                    float* __restrict__ out_u,
                                    float* __restrict__ out_b,
                                    int n_edges) {
    int e = blockIdx.x * blockDim.x + threadIdx.x;
    if (e >= n_edges) return;

    int i1 = index1[e];
    int i2 = index2[e];
    float4 bv = ((const float4*)binary)[e];
    float b[4] = {bv.x, bv.y, bv.z, bv.w};

    const float4* p1 = (const float4*)(u_lo + (size_t)i1 * 8);
    float4 a0 = p1[0], a1 = p1[1];
    const float4* p2 = (const float4*)(u_lo + (size_t)i2 * 8);
    float4 c0 = p2[0], c1 = p2[1];
    float u1[8] = {a0.x,a0.y,a0.z,a0.w,a1.x,a1.y,a1.z,a1.w};
    float u2[8] = {c0.x,c0.y,c0.z,c0.w,c1.x,c1.y,c1.z,c1.w};

    float d1[8], d2[8], dbp[4] = {0.f,0.f,0.f,0.f};
#pragma unroll
    for (int i = 0; i < NC; ++i) {
        float w = bcw[i];
        float a = -u1[i], bb = b[i & 3], c = u2[i];
        float m = fmaxf(a, fmaxf(bb, c));
        float e0 = __expf(a - m);
        float e1 = __expf(bb - m);
        float e2 = __expf(c - m);
        float inv = 1.0f / (e0 + e1 + e2);
        d1[i] = -w * e0 * inv;
        d2[i] =  w * e2 * inv;
        dbp[i & 3] += w * e1 * inv;
    }
    float* r1 = out_u + (size_t)i1 * NU;
#pragma unroll
    for (int i = 0; i < NC; ++i) atomicAdd(r1 + i, d1[i]);
    float* r2 = out_u + (size_t)i2 * NU;
#pragma unroll
    for (int i = 0; i < NC; ++i) atomicAdd(r2 + i, d2[i]);

    float4 ob;
    ob.x = b[0] + dbp[0];
    ob.y = b[1] + dbp[1];
    ob.z = b[2] + dbp[2];
    ob.w = b[3] + dbp[3];
    ((float4*)out_b)[e] = ob;
}

extern "C" void kernel_launch(void* const* d_in, const int* in_sizes, int n_in,
                              void* d_out, int out_size, void* d_ws, size_t ws_size,
                              hipStream_t stream) {
    const float* unary  = (const float*)d_in[0];
    const float* binary = (const float*)d_in[1];
    const float* ucw    = (const float*)d_in[2];
    const float* bcw    = (const float*)d_in[3];
    const int*   index1 = (const int*)d_in[4];
    const int*   index2 = (const int*)d_in[5];

    int n_nodes = in_sizes[0] / NU;
    int n_edges = in_sizes[4];

    float* out_u = (float*)d_out;
    float* out_b = out_u + (size_t)n_nodes * NU;

    int T = (int)(((unsigned)n_nodes + TILE_N - 1) / TILE_N);   // 250
    size_t mean = (2ull * (size_t)n_edges) / (size_t)T;
    int cap = (int)(mean + mean / 8 + 512);
    cap = (cap + 3) & ~3;

    int chunk = (n_edges + NB - 1) / NB;

    // ws layout: u_lo [n_nodes*8 f32] | entries [T*cap uint4] | cursor [T u32]
    size_t u_lo_bytes  = (size_t)n_nodes * 8 * sizeof(float);
    size_t ent_off     = (u_lo_bytes + 15) & ~(size_t)15;
    size_t ent_bytes   = (size_t)T * cap * sizeof(uint4);
    size_t cur_off     = ent_off + ent_bytes;
    size_t cur_bytes   = (size_t)T * 4;
    size_t need        = cur_off + cur_bytes;

    float* u_lo = (float*)d_ws;
    uint4* entries = (uint4*)((char*)d_ws + ent_off);
    unsigned* cursor = (unsigned*)((char*)d_ws + cur_off);

    int tb = 256;
    unary_enhance_kernel<<<(n_nodes + tb - 1) / tb, tb, 0, stream>>>(
        unary, ucw, out_u, u_lo, n_nodes);

    if (ws_size >= need && T <= 256 && chunk <= CACHE_N) {
        (void)hipMemsetAsync(cursor, 0, cur_bytes, stream);
        bin_edges_kernel<<<NB, BT, 0, stream>>>(
            binary, bcw, index1, index2, u_lo, out_b,
            cursor, entries, out_u, n_edges, T, cap, chunk);
        tile_acc_kernel<<<T, 512, 0, stream>>>(
            cursor, entries, out_u, n_nodes, cap);
    } else {
        edge_enhance_kernel<<<(n_edges + tb - 1) / tb, tb, 0, stream>>>(
            binary, bcw, index1, index2, u_lo, out_u, out_b, n_edges);
    }
}